// Round 10
// baseline (123.645 us; speedup 1.0000x reference)
//
#include <hip/hip_runtime.h>
#include <hip/hip_bf16.h>
#include <math.h>

#define Bb 32
#define Nn 400
#define Dd 128
#define Hh 8
#define QKd 16
#define FFd 512
#define Ee 8
#define Tt (Bb*Nn)   // 12800
#define KPAD 424     // VT row stride (bf16 elems)
#define PP2 34       // P row stride (bf16 elems)

typedef __attribute__((ext_vector_type(8))) __bf16 bf16x8;
typedef __attribute__((ext_vector_type(4))) float f32x4;

#if defined(__has_builtin)
#if __has_builtin(__builtin_amdgcn_exp2f)
#define EXP2(x) __builtin_amdgcn_exp2f(x)
#endif
#endif
#ifndef EXP2
#define EXP2(x) __expf((x) * 0.69314718f)
#endif

// RNE f32->bf16 via HW cvt (compiler emits v_cvt_pk_bf16_f32 for pairs).
__device__ __forceinline__ unsigned short f2bfu(float f){
  union { __hip_bfloat16 h; unsigned short u; } v;
  v.h = __float2bfloat16(f);
  return v.u;
}
__device__ __forceinline__ short f2bf(float f){ return (short)f2bfu(f); }
__device__ __forceinline__ unsigned pack2bf(float a, float b){
  return (unsigned)f2bfu(a) | ((unsigned)f2bfu(b) << 16);
}
__device__ __forceinline__ bf16x8 zero_bf16x8(){
  union { uint4 u; bf16x8 b; } z;
  z.u.x = 0u; z.u.y = 0u; z.u.z = 0u; z.u.w = 0u;
  return z.b;
}

// ---------------- K0: prep — all weight transposes (f32 -> bf16^T) + zero gate meta ----------------
__global__ __launch_bounds__(256) void prep_kernel(
    const float* __restrict__ W1, const float* __restrict__ W2, const float* __restrict__ Wo,
    const float* __restrict__ Wq, const float* __restrict__ Wk, const float* __restrict__ Wv,
    short* __restrict__ W1t, short* __restrict__ W2t, short* __restrict__ wo_t,
    short* __restrict__ qkvw, int* __restrict__ gmeta)
{
  const int bid = blockIdx.x;
  if (bid == 0 && threadIdx.x < 24) gmeta[threadIdx.x] = 0;   // cnt[8], imp[8], loadv[8]

  const float* in; short* out; int C, tile;
  if (bid < 512)        { int e = bid >> 6;         tile = bid & 63;          in = W1 + e*65536; out = W1t + e*65536; C = 512; }
  else if (bid < 1024)  { int e = (bid - 512) >> 6; tile = (bid - 512) & 63;  in = W2 + e*65536; out = W2t + e*65536; C = 128; }
  else if (bid < 1040)  { tile = bid - 1024; in = Wo; out = wo_t;          C = 128; }
  else if (bid < 1056)  { tile = bid - 1040; in = Wq; out = qkvw;          C = 128; }
  else if (bid < 1072)  { tile = bid - 1056; in = Wk; out = qkvw + 16384;  C = 128; }
  else                  { tile = bid - 1072; in = Wv; out = qkvw + 32768;  C = 128; }
  const int R = (bid < 512) ? 128 : (bid < 1024 ? 512 : 128);

  __shared__ float t32[32][33];
  const int nCt = C >> 5;
  const int c0 = (tile % nCt) << 5;
  const int r0 = (tile / nCt) << 5;
  const int tx = threadIdx.x & 31, ty = threadIdx.x >> 5;
  #pragma unroll
  for (int i = 0; i < 4; ++i)
    t32[ty + 8*i][tx] = in[(size_t)(r0 + ty + 8*i) * C + c0 + tx];
  __syncthreads();
  #pragma unroll
  for (int i = 0; i < 4; ++i)
    out[(size_t)(c0 + ty + 8*i) * R + r0 + tx] = f2bf(t32[tx][ty + 8*i]);
}

// ---------------- K1: QKV projection via MFMA, split-bf16 activations ----------------
// grid 400, block 256 (32 tokens/block). qkvw: [384][128] bf16. Outputs q,k,v [BH][400][16] bf16.
__global__ __launch_bounds__(256) void qkv_kernel(const float* __restrict__ x,
    const short* __restrict__ qkvw,
    short* __restrict__ q, short* __restrict__ k, short* __restrict__ v)
{
  __shared__ short xsh[32][136];
  __shared__ short xsl[32][136];
  const int tid = threadIdx.x;
  const int t0 = blockIdx.x * 32;

  #pragma unroll
  for (int it = 0; it < 4; ++it) {
    int lin = it * 256 + tid;
    int r = lin >> 5;
    int c4 = (lin & 31) << 2;
    float4 xv = *(const float4*)&x[(size_t)(t0 + r) * Dd + c4];
    unsigned h01 = pack2bf(xv.x, xv.y);
    unsigned h23 = pack2bf(xv.z, xv.w);
    union { unsigned u; float f; } ua, ub, uc, ud;
    ua.u = h01 << 16; ub.u = h01 & 0xFFFF0000u;
    uc.u = h23 << 16; ud.u = h23 & 0xFFFF0000u;
    unsigned l01 = pack2bf(xv.x - ua.f, xv.y - ub.f);
    unsigned l23 = pack2bf(xv.z - uc.f, xv.w - ud.f);
    uint2 ph; ph.x = h01; ph.y = h23;
    uint2 pl; pl.x = l01; pl.y = l23;
    *(uint2*)&xsh[r][c4] = ph;
    *(uint2*)&xsl[r][c4] = pl;
  }
  __syncthreads();

  const int lane = tid & 63, w = tid >> 6;
  const int l15 = lane & 15, l4 = lane >> 4;

  f32x4 zero4 = {0.f, 0.f, 0.f, 0.f};
  f32x4 acc[6][2];
  #pragma unroll
  for (int ot = 0; ot < 6; ++ot)
    #pragma unroll
    for (int mt = 0; mt < 2; ++mt) acc[ot][mt] = zero4;

  #pragma unroll
  for (int kt = 0; kt < 4; ++kt) {
    bf16x8 bmh[2], bml[2];
    #pragma unroll
    for (int mt = 0; mt < 2; ++mt) {
      bmh[mt] = *(const bf16x8*)&xsh[mt*16 + l15][kt*32 + l4*8];
      bml[mt] = *(const bf16x8*)&xsl[mt*16 + l15][kt*32 + l4*8];
    }
    #pragma unroll
    for (int ot = 0; ot < 6; ++ot) {
      bf16x8 a = *(const bf16x8*)&qkvw[(size_t)(w*96 + ot*16 + l15) * Dd + kt*32 + l4*8];
      #pragma unroll
      for (int mt = 0; mt < 2; ++mt) {
        acc[ot][mt] = __builtin_amdgcn_mfma_f32_16x16x32_bf16(a, bmh[mt], acc[ot][mt], 0, 0, 0);
        acc[ot][mt] = __builtin_amdgcn_mfma_f32_16x16x32_bf16(a, bml[mt], acc[ot][mt], 0, 0, 0);
      }
    }
  }

  #pragma unroll
  for (int ot = 0; ot < 6; ++ot) {
    const int ob = w*96 + ot*16;
    const int sel = ob >> 7;
    const int hz = (ob & 127) >> 4;
    #pragma unroll
    for (int mt = 0; mt < 2; ++mt) {
      int t = t0 + mt*16 + l15;
      int b = t / Nn, n = t - b * Nn;
      size_t bhn = (size_t)(b*Hh + hz) * Nn + n;
      f32x4 a = acc[ot][mt];
      uint2 p;
      if (sel == 0) {
        p.x = pack2bf(a[0]*0.36067376f, a[1]*0.36067376f);  // 0.25*log2(e)
        p.y = pack2bf(a[2]*0.36067376f, a[3]*0.36067376f);
        *(uint2*)&q[bhn*16 + l4*4] = p;
      } else if (sel == 1) {
        p.x = pack2bf(a[0], a[1]);
        p.y = pack2bf(a[2], a[3]);
        *(uint2*)&k[bhn*16 + l4*4] = p;
      } else {
        p.x = pack2bf(a[0], a[1]);
        p.y = pack2bf(a[2], a[3]);
        *(uint2*)&v[bhn*16 + l4*4] = p;
      }
    }
  }
}

// ---------------- K2: attention via MFMA (bf16 out), wide grid ----------------
// grid 1280 (= 256 bh x 5 q-groups), block 320 (5 waves; 1 q-tile of 16 rows per wave).
// K loaded directly from global (L1/L2-resident); V^T staged once per block.
__global__ __launch_bounds__(320) void attn_kernel(const short* __restrict__ q,
    const short* __restrict__ k, const short* __restrict__ v, short* __restrict__ attn_b)
{
  __shared__ short VT[16 * KPAD];      // 13568 B
  __shared__ short P[5][16 * PP2];     //  5440 B
  const int tid = threadIdx.x;
  const int bh = blockIdx.x / 5;
  const int qb = blockIdx.x % 5;

  {
    const unsigned* vg = (const unsigned*)(v + (size_t)bh * 400 * 16);
    #pragma unroll
    for (int it = 0; it < 10; ++it) {
      int lin = it*320 + tid;
      int key = lin >> 3, dp = lin & 7;
      unsigned pv = vg[key*8 + dp];
      VT[(2*dp)  * KPAD + key] = (short)(pv & 0xffffu);
      VT[(2*dp+1)* KPAD + key] = (short)(pv >> 16);
    }
    if (tid < 256) {   // zero pad keys 400..415
      int d = tid >> 4, key = 400 + (tid & 15);
      VT[d*KPAD + key] = 0;
    }
  }
  __syncthreads();

  const int w = tid >> 6, lane = tid & 63;
  const int l15 = lane & 15, g = lane >> 4;
  const int q0 = (qb*5 + w) * 16;

  bf16x8 qf;
  if (g < 2) qf = *(const bf16x8*)&q[((size_t)bh*400 + q0 + l15)*16 + 8*g];
  else       qf = zero_bf16x8();
  short* Pw = &P[w][0];

  f32x4 zero4 = {0.f, 0.f, 0.f, 0.f};
  f32x4 o = zero4;
  float lsum = 0.f;

  #pragma unroll
  for (int cc = 0; cc < 13; ++cc) {
    #pragma unroll
    for (int sub = 0; sub < 2; ++sub) {
      const int kt = cc*2 + sub;
      if (kt < 25) {
        bf16x8 kf;
        if (g < 2) kf = *(const bf16x8*)&k[((size_t)bh*400 + kt*16 + l15)*16 + 8*g];
        else       kf = zero_bf16x8();
        f32x4 s = __builtin_amdgcn_mfma_f32_16x16x32_bf16(kf, qf, zero4, 0, 0, 0);
        float p0 = EXP2(s[0]);
        float p1 = EXP2(s[1]);
        float p2 = EXP2(s[2]);
        float p3 = EXP2(s[3]);
        lsum += (p0 + p1) + (p2 + p3);
        uint2 pk;
        pk.x = pack2bf(p0, p1);
        pk.y = pack2bf(p2, p3);
        *(uint2*)&Pw[l15*PP2 + sub*16 + 4*g] = pk;
      } else {   // keys 400..415 -> P = 0
        uint2 z; z.x = 0u; z.y = 0u;
        *(uint2*)&Pw[l15*PP2 + sub*16 + 4*g] = z;
      }
    }
    bf16x8 vf = *(const bf16x8*)&VT[l15*KPAD + cc*32 + 8*g];
    bf16x8 pf = *(const bf16x8*)&Pw[l15*PP2 + 8*g];
    o = __builtin_amdgcn_mfma_f32_16x16x32_bf16(vf, pf, o, 0, 0, 0);
  }

  lsum += __shfl_xor(lsum, 16, 64);
  lsum += __shfl_xor(lsum, 32, 64);
  float inv = 1.f / lsum;

  const int b = bh >> 3, h = bh & 7;
  uint2 pk;
  pk.x = pack2bf(o[0]*inv, o[1]*inv);
  pk.y = pack2bf(o[2]*inv, o[3]*inv);
  *(uint2*)&attn_b[((size_t)b*Nn + q0 + l15)*Dd + h*16 + 4*g] = pk;
}

// ---------------- K3: output proj (MFMA) + residual + LN1 + gating, fused ----------------
// grid 400, block 256 (4 waves x 32 outdims; 32 tokens/block).
__global__ __launch_bounds__(256) void proj_ln1_gate_kernel(
    const float* __restrict__ x, const short* __restrict__ attn_b,
    const short* __restrict__ wo_t, const float* __restrict__ bo,
    const float* __restrict__ g1, const float* __restrict__ b1n,
    const float* __restrict__ w_gate,
    float* __restrict__ out1, short* __restrict__ out1b,
    int* __restrict__ cnt, float* __restrict__ imp, float* __restrict__ loadv,
    int* __restrict__ etok, float* __restrict__ egate)
{
  __shared__ short as_[32][136];
  __shared__ float reds[4][32];
  __shared__ float reds2[4][32];
  __shared__ float mv[32][2];
  __shared__ float lgs[32*8];
  __shared__ float wgs[128*8];
  __shared__ float s_imp[8], s_load[8];
  __shared__ int s_cnt[8], s_base[8];

  const int tid = threadIdx.x;
  const int t0 = blockIdx.x * 32;

  #pragma unroll
  for (int it = 0; it < 4; ++it) {
    int lin = it * 256 + tid;
    int r = lin >> 5;
    int c4 = (lin & 31) << 2;
    *(uint2*)&as_[r][c4] = *(const uint2*)&attn_b[(size_t)(t0 + r) * Dd + c4];
  }
  #pragma unroll
  for (int it = 0; it < 4; ++it) wgs[it*256 + tid] = w_gate[it*256 + tid];
  lgs[tid] = 0.f;
  if (tid < 8) { s_imp[tid] = 0.f; s_load[tid] = 0.f; s_cnt[tid] = 0; }
  __syncthreads();

  const int lane = tid & 63, w = tid >> 6;
  const int l15 = lane & 15, l4 = lane >> 4;

  f32x4 zero4 = {0.f, 0.f, 0.f, 0.f};
  f32x4 y[2][2];
  #pragma unroll
  for (int dt = 0; dt < 2; ++dt)
    #pragma unroll
    for (int mt = 0; mt < 2; ++mt) y[dt][mt] = zero4;

  #pragma unroll
  for (int kt = 0; kt < 4; ++kt) {
    bf16x8 a0 = *(const bf16x8*)&wo_t[(size_t)(w*32 + l15) * Dd + kt*32 + l4*8];
    bf16x8 a1 = *(const bf16x8*)&wo_t[(size_t)(w*32 + 16 + l15) * Dd + kt*32 + l4*8];
    bf16x8 bm[2];
    #pragma unroll
    for (int mt = 0; mt < 2; ++mt)
      bm[mt] = *(const bf16x8*)&as_[mt*16 + l15][kt*32 + l4*8];
    #pragma unroll
    for (int mt = 0; mt < 2; ++mt) {
      y[0][mt] = __builtin_amdgcn_mfma_f32_16x16x32_bf16(a0, bm[mt], y[0][mt], 0, 0, 0);
      y[1][mt] = __builtin_amdgcn_mfma_f32_16x16x32_bf16(a1, bm[mt], y[1][mt], 0, 0, 0);
    }
  }

  float4 bov[2];
  bov[0] = *(const float4*)&bo[w*32 + 0*16 + l4*4];
  bov[1] = *(const float4*)&bo[w*32 + 1*16 + l4*4];
  float sP[2], s2P[2];
  #pragma unroll
  for (int mt = 0; mt < 2; ++mt) { sP[mt] = 0.f; s2P[mt] = 0.f; }
  #pragma unroll
  for (int mt = 0; mt < 2; ++mt) {
    int row = mt*16 + l15;
    #pragma unroll
    for (int dt = 0; dt < 2; ++dt) {
      int dim = w*32 + dt*16 + l4*4;
      float4 xv = *(const float4*)&x[(size_t)(t0 + row) * Dd + dim];
      float4 bv = bov[dt];
      f32x4 r = y[dt][mt];
      r[0] += bv.x + xv.x; r[1] += bv.y + xv.y;
      r[2] += bv.z + xv.z; r[3] += bv.w + xv.w;
      y[dt][mt] = r;
      sP[mt]  += (r[0] + r[1]) + (r[2] + r[3]);
      s2P[mt] += (r[0]*r[0] + r[1]*r[1]) + (r[2]*r[2] + r[3]*r[3]);
    }
  }
  #pragma unroll
  for (int mt = 0; mt < 2; ++mt) {
    sP[mt]  += __shfl_xor(sP[mt], 16, 64);  sP[mt]  += __shfl_xor(sP[mt], 32, 64);
    s2P[mt] += __shfl_xor(s2P[mt], 16, 64); s2P[mt] += __shfl_xor(s2P[mt], 32, 64);
  }
  if (l4 == 0) {
    #pragma unroll
    for (int mt = 0; mt < 2; ++mt) {
      reds[w][mt*16 + l15] = sP[mt];
      reds2[w][mt*16 + l15] = s2P[mt];
    }
  }
  __syncthreads();
  if (tid < 32) {
    float s = reds[0][tid] + reds[1][tid] + reds[2][tid] + reds[3][tid];
    float s2 = reds2[0][tid] + reds2[1][tid] + reds2[2][tid] + reds2[3][tid];
    float m = s * (1.f/128.f);
    float var = s2 * (1.f/128.f) - m*m;
    mv[tid][0] = m;
    mv[tid][1] = rsqrtf(var + 1e-5f);
  }
  __syncthreads();

  float4 gv[2], bv2[2];
  #pragma unroll
  for (int dt = 0; dt < 2; ++dt) {
    gv[dt]  = *(const float4*)&g1[w*32 + dt*16 + l4*4];
    bv2[dt] = *(const float4*)&b1n[w*32 + dt*16 + l4*4];
  }
  #pragma unroll
  for (int mt = 0; mt < 2; ++mt) {
    int row = mt*16 + l15;
    float m = mv[row][0], inv = mv[row][1];
    float lg[8];
    #pragma unroll
    for (int e = 0; e < 8; ++e) lg[e] = 0.f;
    #pragma unroll
    for (int dt = 0; dt < 2; ++dt) {
      int dim = w*32 + dt*16 + l4*4;
      f32x4 r = y[dt][mt];
      float o0 = (r[0]-m)*inv*((float*)&gv[dt])[0] + ((float*)&bv2[dt])[0];
      float o1 = (r[1]-m)*inv*((float*)&gv[dt])[1] + ((float*)&bv2[dt])[1];
      float o2 = (r[2]-m)*inv*((float*)&gv[dt])[2] + ((float*)&bv2[dt])[2];
      float o3 = (r[3]-m)*inv*((float*)&gv[dt])[3] + ((float*)&bv2[dt])[3];
      float4 ov; ov.x = o0; ov.y = o1; ov.z = o2; ov.w = o3;
      *(float4*)&out1[(size_t)(t0 + row) * Dd + dim] = ov;
      uint2 p; p.x = pack2bf(o0, o1); p.y = pack2bf(o2, o3);
      *(uint2*)&out1b[(size_t)(t0 + row) * Dd + dim] = p;
      #pragma unroll
      for (int e = 0; e < 8; ++e)
        lg[e] += o0*wgs[(dim+0)*8+e] + o1*wgs[(dim+1)*8+e]
               + o2*wgs[(dim+2)*8+e] + o3*wgs[(dim+3)*8+e];
    }
    #pragma unroll
    for (int e = 0; e < 8; ++e) {
      lg[e] += __shfl_xor(lg[e], 16, 64);
      lg[e] += __shfl_xor(lg[e], 32, 64);
    }
    if (l4 == 0) {
      #pragma unroll
      for (int e = 0; e < 8; ++e) atomicAdd(&lgs[row*8 + e], lg[e]);
    }
  }
  __syncthreads();

  int i0 = 0, i1 = -1, p0 = 0, p1 = 0;
  float g0 = 0.f, gg1 = 0.f;
  if (tid < 32) {
    float lgv[8];
    #pragma unroll
    for (int e = 0; e < 8; ++e) lgv[e] = lgs[tid*8 + e];
    float v0 = lgv[0];
    #pragma unroll
    for (int e = 1; e < 8; ++e) if (lgv[e] > v0) { v0 = lgv[e]; i0 = e; }
    float v1 = -INFINITY;
    #pragma unroll
    for (int e = 0; e < 8; ++e) if (e != i0 && lgv[e] > v1) { v1 = lgv[e]; i1 = e; }
    g0 = 1.f / (1.f + __expf(v1 - v0));
    gg1 = 1.f - g0;
    atomicAdd(&s_imp[i0], g0);  atomicAdd(&s_imp[i1], gg1);
    atomicAdd(&s_load[i0], 1.f); atomicAdd(&s_load[i1], 1.f);
    p0 = atomicAdd(&s_cnt[i0], 1);
    p1 = atomicAdd(&s_cnt[i1], 1);
  }
  __syncthreads();
  if (tid < 8) {
    s_base[tid] = atomicAdd(&cnt[tid], s_cnt[tid]);
    atomicAdd(&imp[tid], s_imp[tid]);
    atomicAdd(&loadv[tid], s_load[tid]);
  }
  __syncthreads();
  if (tid < 32) {
    int t = t0 + tid;
    int o0 = i0 * Tt + s_base[i0] + p0;
    etok[o0] = t;               egate[o0] = g0;
    int o1 = i1 * Tt + s_base[i1] + p1;
    etok[o1] = t | (1 << 30);   egate[o1] = gg1;
  }
}

// ---------------- K6: grouped sparse MoE FFN (MFMA bf16, bf16 in/out) ----------------
__global__ __launch_bounds__(256) void moe_kernel(const short* __restrict__ out1b,
    const short* __restrict__ W1t, const float* __restrict__ b1,
    const short* __restrict__ W2t, const float* __restrict__ b2,
    const int* __restrict__ cnt, const int* __restrict__ etok, const float* __restrict__ egate,
    short* __restrict__ moe0, short* __restrict__ moe1)
{
  __shared__ short xs[64][136];
  __shared__ short hs[64][136];
  __shared__ int els[64];
  __shared__ float gls[64];

  const int e = blockIdx.y;
  const int count = cnt[e];
  const int t0 = blockIdx.x * 64;
  if (t0 >= count) return;
  const int nt = min(64, count - t0);
  const int tid = threadIdx.x;

  if (tid < 64) {
    int idx = (tid < nt) ? tid : 0;
    els[tid] = etok[e * Tt + t0 + idx];
    gls[tid] = (tid < nt) ? egate[e * Tt + t0 + tid] : 0.f;
  }
  __syncthreads();

  #pragma unroll
  for (int it = 0; it < 8; ++it) {
    int lin = it * 256 + tid;
    int r = lin >> 5;
    int c4 = (lin & 31) << 2;
    int tok = els[r] & 0x3FFFFFFF;
    *(uint2*)&xs[r][c4] = *(const uint2*)&out1b[(size_t)tok * Dd + c4];
  }
  __syncthreads();

  const int lane = tid & 63;
  const int w = tid >> 6;
  const int l15 = lane & 15;
  const int l4 = lane >> 4;

  f32x4 zero4 = {0.f, 0.f, 0.f, 0.f};
  f32x4 y[2][4];
  #pragma unroll
  for (int dt = 0; dt < 2; ++dt)
    #pragma unroll
    for (int mt = 0; mt < 4; ++mt) y[dt][mt] = zero4;

  const short* W1p = W1t + (size_t)e * FFd * Dd;
  const short* W2p = W2t + (size_t)e * Dd * FFd;

  for (int ch = 0; ch < 4; ++ch) {
    f32x4 h[2][4];
    #pragma unroll
    for (int ft = 0; ft < 2; ++ft)
      #pragma unroll
      for (int mt = 0; mt < 4; ++mt) h[ft][mt] = zero4;

    #pragma unroll
    for (int kt = 0; kt < 4; ++kt) {
      bf16x8 a0 = *(const bf16x8*)&W1p[(size_t)(ch*128 + w*32 + 0*16 + l15) * Dd + kt*32 + l4*8];
      bf16x8 a1 = *(const bf16x8*)&W1p[(size_t)(ch*128 + w*32 + 1*16 + l15) * Dd + kt*32 + l4*8];
      bf16x8 bm[4];
      #pragma unroll
      for (int mt = 0; mt < 4; ++mt)
        bm[mt] = *(const bf16x8*)&xs[mt*16 + l15][kt*32 + l4*8];
      #pragma unroll
      for (int mt = 0; mt < 4; ++mt) {
        h[0][mt] = __builtin_amdgcn_mfma_f32_16x16x32_bf16(a0, bm[mt], h[0][mt], 0, 0, 0);
        h[1][mt] = __builtin_amdgcn_mfma_f32_16x16x32_bf16(a1, bm[mt], h[1][mt], 0, 0, 0);
      }
    }

    float4 b1v0 = *(const float4*)&b1[e*FFd + ch*128 + w*32 + 0*16 + l4*4];
    float4 b1v1 = *(const float4*)&b1[e*FFd + ch*128 + w*32 + 1*16 + l4*4];
    __syncthreads();
    #pragma unroll
    for (int mt = 0; mt < 4; ++mt) {
      uint2 p0, p1;
      p0.x = pack2bf(fmaxf(h[0][mt][0] + b1v0.x, 0.f), fmaxf(h[0][mt][1] + b1v0.y, 0.f));
      p0.y = pack2bf(fmaxf(h[0][mt][2] + b1v0.z, 0.f), fmaxf(h[0][mt][3] + b1v0.w, 0.f));
      *(uint2*)&hs[mt*16 + l15][w*32 + 0*16 + l4*4] = p0;
      p1.x = pack2bf(fmaxf(h[1][mt][0] + b1v1.x, 0.f), fmaxf(h[1][mt][1] + b1v1.y, 0.f));
      p1.y = pack2bf(fmaxf(h[1][mt][2] + b1v1.z, 0.f), fmaxf(h[1][mt][3] + b1v1.w, 0.f));
      *(uint2*)&hs[mt*16 + l15][w*32 + 1*16 + l4*4] = p1;
    }
    __syncthreads();

    #pragma unroll
    for (int kt = 0; kt < 4; ++kt) {
      bf16x8 a0 = *(const bf16x8*)&W2p[(size_t)(w*32 + 0*16 + l15) * FFd + ch*128 + kt*32 + l4*8];
      bf16x8 a1 = *(const bf16x8*)&W2p[(size_t)(w*32 + 1*16 + l15) * FFd + ch*128 + kt*32 + l4*8];
      bf16x8 bm[4];
      #pragma unroll
      for (int mt = 0; mt < 4; ++mt)
        bm[mt] = *(const bf16x8*)&hs[mt*16 + l15][kt*32 + l4*8];
      #pragma unroll
      for (int mt = 0; mt < 4; ++mt) {
        y[0][mt] = __builtin_amdgcn_mfma_f32_16x16x32_bf16(a0, bm[mt], y[0][mt], 0, 0, 0);
        y[1][mt] = __builtin_amdgcn_mfma_f32_16x16x32_bf16(a1, bm[mt], y[1][mt], 0, 0, 0);
      }
    }
  }

  float4 b2v[2];
  b2v[0] = *(const float4*)&b2[e*Dd + w*32 + 0*16 + l4*4];
  b2v[1] = *(const float4*)&b2[e*Dd + w*32 + 1*16 + l4*4];
  #pragma unroll
  for (int mt = 0; mt < 4; ++mt) {
    int m = mt*16 + l15;
    if (m < nt) {
      int raw = els[m];
      int t = raw & 0x3FFFFFFF;
      float g = gls[m];
      short* basep = (raw & (1 << 30)) ? moe1 : moe0;
      #pragma unroll
      for (int dt = 0; dt < 2; ++dt) {
        float v0 = g * (y[dt][mt][0] + ((dt == 0) ? b2v[0].x : b2v[1].x));
        float v1 = g * (y[dt][mt][1] + ((dt == 0) ? b2v[0].y : b2v[1].y));
        float v2 = g * (y[dt][mt][2] + ((dt == 0) ? b2v[0].z : b2v[1].z));
        float v3 = g * (y[dt][mt][3] + ((dt == 0) ? b2v[0].w : b2v[1].w));
        uint2 p; p.x = pack2bf(v0, v1); p.y = pack2bf(v2, v3);
        *(uint2*)&basep[(size_t)t * Dd + w*32 + dt*16 + l4*4] = p;
      }
    }
  }
}

// ---------------- K7: residual + LN2 -> d_out (+ loss in block 0) ----------------
// grid 3200, block 256 (one wave per token; no LDS).
__global__ __launch_bounds__(256) void ln2_kernel(const float* __restrict__ out1,
    const short* __restrict__ moe0, const short* __restrict__ moe1,
    const float* __restrict__ g, const float* __restrict__ bb,
    const float* __restrict__ imp, const float* __restrict__ loadv,
    float* __restrict__ out, float* __restrict__ out_loss)
{
  const int tid = threadIdx.x;
  const int lane = tid & 63;
  const int t = blockIdx.x * 4 + (tid >> 6);
  const int j = lane * 2;

  float2 xv = *(const float2*)&out1[(size_t)t * Dd + j];
  unsigned m0 = *(const unsigned*)&moe0[(size_t)t * Dd + j];
  unsigned m1 = *(const unsigned*)&moe1[(size_t)t * Dd + j];
  union { unsigned u; float f; } a, b, c, d;
  a.u = m0 << 16; b.u = m0 & 0xFFFF0000u;
  c.u = m1 << 16; d.u = m1 & 0xFFFF0000u;
  float r0 = xv.x + a.f + c.f;
  float r1 = xv.y + b.f + d.f;

  float s = r0 + r1;
  float s2 = r0*r0 + r1*r1;
  #pragma unroll
  for (int off = 32; off > 0; off >>= 1) {
    s  += __shfl_xor(s, off, 64);
    s2 += __shfl_xor(s2, off, 64);
  }
  float mean = s * (1.f/128.f);
  float var = s2 * (1.f/128.f) - mean*mean;
  float inv = rsqrtf(var + 1e-5f);
  float2 ov;
  ov.x = (r0 - mean) * inv * g[j]   + bb[j];
  ov.y = (r1 - mean) * inv * g[j+1] + bb[j+1];
  *(float2*)&out[(size_t)t * Dd + j] = ov;

  if (blockIdx.x == 0 && tid == 0) {
    float m1s = 0.f;
    for (int e = 0; e < 8; ++e) m1s += imp[e];
    m1s *= 0.125f;
    float v1 = 0.f;
    for (int e = 0; e < 8; ++e) { float dd = imp[e] - m1s; v1 += dd * dd; }
    v1 *= 0.125f;
    float c1 = v1 / (m1s * m1s + 1e-10f);
    float m2 = 0.f;
    for (int e = 0; e < 8; ++e) m2 += loadv[e];
    m2 *= 0.125f;
    float v2 = 0.f;
    for (int e = 0; e < 8; ++e) { float dd = loadv[e] - m2; v2 += dd * dd; }
    v2 *= 0.125f;
    float c2 = v2 / (m2 * m2 + 1e-10f);
    out_loss[0] = (c1 + c2) * 0.01f;
  }
}

extern "C" void kernel_launch(void* const* d_in, const int* in_sizes, int n_in,
                              void* d_out, int out_size, void* d_ws, size_t ws_size,
                              hipStream_t stream)
{
  (void)in_sizes; (void)n_in; (void)out_size; (void)ws_size;
  const float* x      = (const float*)d_in[0];
  const float* Wq     = (const float*)d_in[1];
  const float* Wk     = (const float*)d_in[2];
  const float* Wv     = (const float*)d_in[3];
  const float* Wo     = (const float*)d_in[4];
  const float* bo     = (const float*)d_in[5];
  const float* ln1_g  = (const float*)d_in[6];
  const float* ln1_b  = (const float*)d_in[7];
  const float* w_gate = (const float*)d_in[8];
  const float* W1     = (const float*)d_in[9];
  const float* b1     = (const float*)d_in[10];
  const float* W2     = (const float*)d_in[11];
  const float* b2     = (const float*)d_in[12];
  const float* ln2_g  = (const float*)d_in[13];
  const float* ln2_b  = (const float*)d_in[14];

  char* wsb = (char*)d_ws;
  size_t off = 0;
  short* attn_b  = (short*)(wsb + off); off += (size_t)Tt*Dd*2;          //  3,276,800
  float* out1    = (float*)(wsb + off); off += (size_t)Tt*Dd*4;          //  6,553,600
  short* out1b   = (short*)(wsb + off); off += (size_t)Tt*Dd*2;          //  3,276,800
  short* moe0    = (short*)(wsb + off); off += (size_t)Tt*Dd*2;          //  3,276,800
  short* moe1    = (short*)(wsb + off); off += (size_t)Tt*Dd*2;          //  3,276,800
  short* q_bf    = (short*)(wsb + off); off += (size_t)256*400*16*2;     //  3,276,800
  short* k_bf    = (short*)(wsb + off); off += (size_t)256*400*16*2;     //  3,276,800
  short* v_bf    = (short*)(wsb + off); off += (size_t)256*400*16*2;     //  3,276,800
  short* W1t     = (short*)(wsb + off); off += (size_t)Ee*FFd*Dd*2;      //  1,048,576
  short* W2t     = (short*)(wsb + off); off += (size_t)Ee*FFd*Dd*2;      //  1,048,576
  short* wo_t    = (short*)(wsb + off); off += (size_t)Dd*Dd*2;          //     32,768
  short* qkvw    = (short*)(wsb + off); off += (size_t)384*Dd*2;         //     98,304
  int*   gmeta   = (int*)(wsb + off);   off += 256;
  int*   etok    = (int*)(wsb + off);   off += (size_t)Ee*Tt*4;          //    409,600
  float* egate   = (float*)(wsb + off); off += (size_t)Ee*Tt*4;          //    409,600

  int*   cnt   = gmeta;
  float* imp   = (float*)(gmeta + 8);
  float* loadv = (float*)(gmeta + 16);

  float* out3 = (float*)d_out;
  float* loss = out3 + Tt * Dd;

  prep_kernel<<<1088, 256, 0, stream>>>(W1, W2, Wo, Wq, Wk, Wv, W1t, W2t, wo_t, qkvw, gmeta);
  qkv_kernel<<<400, 256, 0, stream>>>(x, qkvw, q_bf, k_bf, v_bf);
  attn_kernel<<<1280, 320, 0, stream>>>(q_bf, k_bf, v_bf, attn_b);
  proj_ln1_gate_kernel<<<400, 256, 0, stream>>>(x, attn_b, wo_t, bo, ln1_g, ln1_b, w_gate,
                                                out1, out1b, cnt, imp, loadv, etok, egate);
  moe_kernel<<<dim3(200, 8), 256, 0, stream>>>(out1b, W1t, b1, W2t, b2, cnt, etok, egate, moe0, moe1);
  ln2_kernel<<<3200, 256, 0, stream>>>(out1, moe0, moe1, ln2_g, ln2_b, imp, loadv, out3, loss);
}

// Round 11
// 114.787 us; speedup vs baseline: 1.0772x; 1.0772x over previous
//
#include <hip/hip_runtime.h>
#include <hip/hip_bf16.h>
#include <math.h>

#define Bb 32
#define Nn 400
#define Dd 128
#define Hh 8
#define QKd 16
#define FFd 512
#define Ee 8
#define Tt (Bb*Nn)   // 12800
#define KPAD 434     // VT row stride (bf16): 217 dwords, odd -> bank-conflict-free PV reads
#define PP2 34       // P row stride (bf16 elems)

typedef __attribute__((ext_vector_type(8))) __bf16 bf16x8;
typedef __attribute__((ext_vector_type(4))) float f32x4;

#if defined(__has_builtin)
#if __has_builtin(__builtin_amdgcn_exp2f)
#define EXP2(x) __builtin_amdgcn_exp2f(x)
#endif
#endif
#ifndef EXP2
#define EXP2(x) __expf((x) * 0.69314718f)
#endif

// RNE f32->bf16 via HW cvt (compiler emits v_cvt_pk_bf16_f32 for pairs).
__device__ __forceinline__ unsigned short f2bfu(float f){
  union { __hip_bfloat16 h; unsigned short u; } v;
  v.h = __float2bfloat16(f);
  return v.u;
}
__device__ __forceinline__ short f2bf(float f){ return (short)f2bfu(f); }
__device__ __forceinline__ unsigned pack2bf(float a, float b){
  return (unsigned)f2bfu(a) | ((unsigned)f2bfu(b) << 16);
}
__device__ __forceinline__ bf16x8 zero_bf16x8(){
  union { uint4 u; bf16x8 b; } z;
  z.u.x = 0u; z.u.y = 0u; z.u.z = 0u; z.u.w = 0u;
  return z.b;
}

// ---------------- K0: prep — all weight transposes (f32 -> bf16^T) + zero gate meta ----------------
__global__ __launch_bounds__(256) void prep_kernel(
    const float* __restrict__ W1, const float* __restrict__ W2, const float* __restrict__ Wo,
    const float* __restrict__ Wq, const float* __restrict__ Wk, const float* __restrict__ Wv,
    short* __restrict__ W1t, short* __restrict__ W2t, short* __restrict__ wo_t,
    short* __restrict__ qkvw, int* __restrict__ gmeta)
{
  const int bid = blockIdx.x;
  if (bid == 0 && threadIdx.x < 24) gmeta[threadIdx.x] = 0;   // cnt[8], imp[8], loadv[8]

  const float* in; short* out; int C, tile;
  if (bid < 512)        { int e = bid >> 6;         tile = bid & 63;          in = W1 + e*65536; out = W1t + e*65536; C = 512; }
  else if (bid < 1024)  { int e = (bid - 512) >> 6; tile = (bid - 512) & 63;  in = W2 + e*65536; out = W2t + e*65536; C = 128; }
  else if (bid < 1040)  { tile = bid - 1024; in = Wo; out = wo_t;          C = 128; }
  else if (bid < 1056)  { tile = bid - 1040; in = Wq; out = qkvw;          C = 128; }
  else if (bid < 1072)  { tile = bid - 1056; in = Wk; out = qkvw + 16384;  C = 128; }
  else                  { tile = bid - 1072; in = Wv; out = qkvw + 32768;  C = 128; }
  const int R = (bid < 512) ? 128 : (bid < 1024 ? 512 : 128);

  __shared__ float t32[32][33];
  const int nCt = C >> 5;
  const int c0 = (tile % nCt) << 5;
  const int r0 = (tile / nCt) << 5;
  const int tx = threadIdx.x & 31, ty = threadIdx.x >> 5;
  #pragma unroll
  for (int i = 0; i < 4; ++i)
    t32[ty + 8*i][tx] = in[(size_t)(r0 + ty + 8*i) * C + c0 + tx];
  __syncthreads();
  #pragma unroll
  for (int i = 0; i < 4; ++i)
    out[(size_t)(c0 + ty + 8*i) * R + r0 + tx] = f2bf(t32[tx][ty + 8*i]);
}

// ---------------- K1: QKV projection via MFMA, split-bf16 activations ----------------
// grid 200, block 256. qkvw: [384][128] bf16. Outputs q,k,v all [BH][400][16] bf16 (q pre-scaled).
__global__ __launch_bounds__(256) void qkv_kernel(const float* __restrict__ x,
    const short* __restrict__ qkvw,
    short* __restrict__ q, short* __restrict__ k, short* __restrict__ v)
{
  __shared__ short xsh[64][136];
  __shared__ short xsl[64][136];
  const int tid = threadIdx.x;
  const int t0 = blockIdx.x * 64;

  #pragma unroll
  for (int it = 0; it < 8; ++it) {
    int lin = it * 256 + tid;
    int r = lin >> 5;
    int c4 = (lin & 31) << 2;
    float4 xv = *(const float4*)&x[(size_t)(t0 + r) * Dd + c4];
    unsigned h01 = pack2bf(xv.x, xv.y);
    unsigned h23 = pack2bf(xv.z, xv.w);
    union { unsigned u; float f; } ua, ub, uc, ud;
    ua.u = h01 << 16; ub.u = h01 & 0xFFFF0000u;
    uc.u = h23 << 16; ud.u = h23 & 0xFFFF0000u;
    unsigned l01 = pack2bf(xv.x - ua.f, xv.y - ub.f);
    unsigned l23 = pack2bf(xv.z - uc.f, xv.w - ud.f);
    uint2 ph; ph.x = h01; ph.y = h23;
    uint2 pl; pl.x = l01; pl.y = l23;
    *(uint2*)&xsh[r][c4] = ph;
    *(uint2*)&xsl[r][c4] = pl;
  }
  __syncthreads();

  const int lane = tid & 63, w = tid >> 6;
  const int l15 = lane & 15, l4 = lane >> 4;

  f32x4 zero4 = {0.f, 0.f, 0.f, 0.f};
  f32x4 acc[6][4];
  #pragma unroll
  for (int ot = 0; ot < 6; ++ot)
    #pragma unroll
    for (int mt = 0; mt < 4; ++mt) acc[ot][mt] = zero4;

  #pragma unroll
  for (int kt = 0; kt < 4; ++kt) {
    bf16x8 bmh[4], bml[4];
    #pragma unroll
    for (int mt = 0; mt < 4; ++mt) {
      bmh[mt] = *(const bf16x8*)&xsh[mt*16 + l15][kt*32 + l4*8];
      bml[mt] = *(const bf16x8*)&xsl[mt*16 + l15][kt*32 + l4*8];
    }
    #pragma unroll
    for (int ot = 0; ot < 6; ++ot) {
      bf16x8 a = *(const bf16x8*)&qkvw[(size_t)(w*96 + ot*16 + l15) * Dd + kt*32 + l4*8];
      #pragma unroll
      for (int mt = 0; mt < 4; ++mt) {
        acc[ot][mt] = __builtin_amdgcn_mfma_f32_16x16x32_bf16(a, bmh[mt], acc[ot][mt], 0, 0, 0);
        acc[ot][mt] = __builtin_amdgcn_mfma_f32_16x16x32_bf16(a, bml[mt], acc[ot][mt], 0, 0, 0);
      }
    }
  }

  #pragma unroll
  for (int ot = 0; ot < 6; ++ot) {
    const int ob = w*96 + ot*16;
    const int sel = ob >> 7;
    const int hz = (ob & 127) >> 4;
    #pragma unroll
    for (int mt = 0; mt < 4; ++mt) {
      int t = t0 + mt*16 + l15;
      int b = t / Nn, n = t - b * Nn;
      size_t bhn = (size_t)(b*Hh + hz) * Nn + n;
      f32x4 a = acc[ot][mt];
      uint2 p;
      if (sel == 0) {
        p.x = pack2bf(a[0]*0.36067376f, a[1]*0.36067376f);  // 0.25*log2(e)
        p.y = pack2bf(a[2]*0.36067376f, a[3]*0.36067376f);
        *(uint2*)&q[bhn*16 + l4*4] = p;
      } else if (sel == 1) {
        p.x = pack2bf(a[0], a[1]);
        p.y = pack2bf(a[2], a[3]);
        *(uint2*)&k[bhn*16 + l4*4] = p;
      } else {
        p.x = pack2bf(a[0], a[1]);
        p.y = pack2bf(a[2], a[3]);
        *(uint2*)&v[bhn*16 + l4*4] = p;
      }
    }
  }
}

// ---------------- K2: attention via MFMA, one block per bh (bf16 out), slim LDS ----------------
// grid 256, block 512 (8 waves). Wave w owns q-tiles {w, w+8, w+16, w+24} (<25).
// Per 32-key chunk: kf0/kf1 held in registers (loaded once), P is per-wave only.
__global__ __launch_bounds__(512) void attn_kernel(const short* __restrict__ q,
    const short* __restrict__ k, const short* __restrict__ v, short* __restrict__ attn_b)
{
  __shared__ short VT[16 * KPAD];      // 13888 B
  __shared__ short P[8][16 * PP2];     //  8704 B  -> total 22592 B
  const int tid = threadIdx.x;
  const int bh = blockIdx.x;

  {
    const unsigned* vg = (const unsigned*)(v + (size_t)bh * 400 * 16);
    #pragma unroll
    for (int it = 0; it < 7; ++it) {
      int lin = it*512 + tid;
      if (lin < 3200) {
        int key = lin >> 3, dp = lin & 7;
        unsigned pv = vg[key*8 + dp];
        VT[(2*dp)  * KPAD + key] = (short)(pv & 0xffffu);
        VT[(2*dp+1)* KPAD + key] = (short)(pv >> 16);
      }
    }
    if (tid < 256) {   // zero pad keys 400..415
      int d = tid >> 4, key = 400 + (tid & 15);
      VT[d*KPAD + key] = 0;
    }
  }
  __syncthreads();

  const int w = tid >> 6, lane = tid & 63;
  const int l15 = lane & 15, g = lane >> 4;

  f32x4 zero4 = {0.f, 0.f, 0.f, 0.f};
  f32x4 o[4];
  float lsum[4];
  bf16x8 qf[4];
  #pragma unroll
  for (int i = 0; i < 4; ++i) {
    o[i] = zero4; lsum[i] = 0.f;
    int qt = w + 8*i;
    if (qt < 25 && g < 2)
      qf[i] = *(const bf16x8*)&q[((size_t)bh*400 + qt*16 + l15)*16 + 8*g];
    else
      qf[i] = zero_bf16x8();
  }

  short* Pw = &P[w][0];

  #pragma unroll
  for (int cc = 0; cc < 13; ++cc) {
    const int kt0 = cc*2, kt1 = cc*2 + 1;
    bf16x8 kf0, kf1;
    if (g < 2) kf0 = *(const bf16x8*)&k[((size_t)bh*400 + kt0*16 + l15)*16 + 8*g];
    else       kf0 = zero_bf16x8();
    if (kt1 < 25 && g < 2) kf1 = *(const bf16x8*)&k[((size_t)bh*400 + kt1*16 + l15)*16 + 8*g];
    else                   kf1 = zero_bf16x8();
    bf16x8 vf = *(const bf16x8*)&VT[l15*KPAD + cc*32 + 8*g];

    #pragma unroll
    for (int i = 0; i < 4; ++i) {
      int qt = w + 8*i;
      if (qt < 25) {
        f32x4 s0 = __builtin_amdgcn_mfma_f32_16x16x32_bf16(kf0, qf[i], zero4, 0, 0, 0);
        float a0 = EXP2(s0[0]);
        float a1 = EXP2(s0[1]);
        float a2 = EXP2(s0[2]);
        float a3 = EXP2(s0[3]);
        lsum[i] += (a0 + a1) + (a2 + a3);
        uint2 pk0;
        pk0.x = pack2bf(a0, a1);
        pk0.y = pack2bf(a2, a3);
        uint2 pk1;
        if (kt1 < 25) {
          f32x4 s1 = __builtin_amdgcn_mfma_f32_16x16x32_bf16(kf1, qf[i], zero4, 0, 0, 0);
          float b0 = EXP2(s1[0]);
          float b1 = EXP2(s1[1]);
          float b2 = EXP2(s1[2]);
          float b3 = EXP2(s1[3]);
          lsum[i] += (b0 + b1) + (b2 + b3);
          pk1.x = pack2bf(b0, b1);
          pk1.y = pack2bf(b2, b3);
        } else {
          pk1.x = 0u; pk1.y = 0u;
        }
        *(uint2*)&Pw[l15*PP2 + 4*g] = pk0;
        *(uint2*)&Pw[l15*PP2 + 16 + 4*g] = pk1;
        bf16x8 pf = *(const bf16x8*)&Pw[l15*PP2 + 8*g];
        o[i] = __builtin_amdgcn_mfma_f32_16x16x32_bf16(vf, pf, o[i], 0, 0, 0);
      }
    }
  }

  const int b = bh >> 3, h = bh & 7;
  #pragma unroll
  for (int i = 0; i < 4; ++i) {
    int qt = w + 8*i;
    if (qt < 25) {
      float ls = lsum[i];
      ls += __shfl_xor(ls, 16, 64);
      ls += __shfl_xor(ls, 32, 64);
      float inv = 1.f / ls;
      uint2 pk;
      pk.x = pack2bf(o[i][0]*inv, o[i][1]*inv);
      pk.y = pack2bf(o[i][2]*inv, o[i][3]*inv);
      *(uint2*)&attn_b[((size_t)b*Nn + qt*16 + l15)*Dd + h*16 + 4*g] = pk;
    }
  }
}

// ---------------- K3: output proj (MFMA) + residual + LN1 + gating, fused ----------------
// grid 200, block 256 (4 waves x 32 outdims; 64 tokens/block).
__global__ __launch_bounds__(256) void proj_ln1_gate_kernel(
    const float* __restrict__ x, const short* __restrict__ attn_b,
    const short* __restrict__ wo_t, const float* __restrict__ bo,
    const float* __restrict__ g1, const float* __restrict__ b1n,
    const float* __restrict__ w_gate,
    float* __restrict__ out1, short* __restrict__ out1b,
    int* __restrict__ cnt, float* __restrict__ imp, float* __restrict__ loadv,
    int* __restrict__ etok, float* __restrict__ egate)
{
  __shared__ short as_[64][136];
  __shared__ float reds[4][64];
  __shared__ float reds2[4][64];
  __shared__ float mv[64][2];
  __shared__ float lgs[64*8];
  __shared__ float wgs[128*8];
  __shared__ float s_imp[8], s_load[8];
  __shared__ int s_cnt[8], s_base[8];

  const int tid = threadIdx.x;
  const int t0 = blockIdx.x * 64;

  #pragma unroll
  for (int it = 0; it < 8; ++it) {
    int lin = it * 256 + tid;
    int r = lin >> 5;
    int c4 = (lin & 31) << 2;
    *(uint2*)&as_[r][c4] = *(const uint2*)&attn_b[(size_t)(t0 + r) * Dd + c4];
  }
  #pragma unroll
  for (int it = 0; it < 4; ++it) wgs[it*256 + tid] = w_gate[it*256 + tid];
  lgs[tid] = 0.f; lgs[tid + 256] = 0.f;
  if (tid < 8) { s_imp[tid] = 0.f; s_load[tid] = 0.f; s_cnt[tid] = 0; }
  __syncthreads();

  const int lane = tid & 63, w = tid >> 6;
  const int l15 = lane & 15, l4 = lane >> 4;

  f32x4 zero4 = {0.f, 0.f, 0.f, 0.f};
  f32x4 y[2][4];
  #pragma unroll
  for (int dt = 0; dt < 2; ++dt)
    #pragma unroll
    for (int mt = 0; mt < 4; ++mt) y[dt][mt] = zero4;

  #pragma unroll
  for (int kt = 0; kt < 4; ++kt) {
    bf16x8 a0 = *(const bf16x8*)&wo_t[(size_t)(w*32 + l15) * Dd + kt*32 + l4*8];
    bf16x8 a1 = *(const bf16x8*)&wo_t[(size_t)(w*32 + 16 + l15) * Dd + kt*32 + l4*8];
    bf16x8 bm[4];
    #pragma unroll
    for (int mt = 0; mt < 4; ++mt)
      bm[mt] = *(const bf16x8*)&as_[mt*16 + l15][kt*32 + l4*8];
    #pragma unroll
    for (int mt = 0; mt < 4; ++mt) {
      y[0][mt] = __builtin_amdgcn_mfma_f32_16x16x32_bf16(a0, bm[mt], y[0][mt], 0, 0, 0);
      y[1][mt] = __builtin_amdgcn_mfma_f32_16x16x32_bf16(a1, bm[mt], y[1][mt], 0, 0, 0);
    }
  }

  float4 bov[2];
  bov[0] = *(const float4*)&bo[w*32 + 0*16 + l4*4];
  bov[1] = *(const float4*)&bo[w*32 + 1*16 + l4*4];
  float sP[4], s2P[4];
  #pragma unroll
  for (int mt = 0; mt < 4; ++mt) { sP[mt] = 0.f; s2P[mt] = 0.f; }
  #pragma unroll
  for (int mt = 0; mt < 4; ++mt) {
    int row = mt*16 + l15;
    #pragma unroll
    for (int dt = 0; dt < 2; ++dt) {
      int dim = w*32 + dt*16 + l4*4;
      float4 xv = *(const float4*)&x[(size_t)(t0 + row) * Dd + dim];
      float4 bv = bov[dt];
      f32x4 r = y[dt][mt];
      r[0] += bv.x + xv.x; r[1] += bv.y + xv.y;
      r[2] += bv.z + xv.z; r[3] += bv.w + xv.w;
      y[dt][mt] = r;
      sP[mt]  += (r[0] + r[1]) + (r[2] + r[3]);
      s2P[mt] += (r[0]*r[0] + r[1]*r[1]) + (r[2]*r[2] + r[3]*r[3]);
    }
  }
  #pragma unroll
  for (int mt = 0; mt < 4; ++mt) {
    sP[mt]  += __shfl_xor(sP[mt], 16, 64);  sP[mt]  += __shfl_xor(sP[mt], 32, 64);
    s2P[mt] += __shfl_xor(s2P[mt], 16, 64); s2P[mt] += __shfl_xor(s2P[mt], 32, 64);
  }
  if (l4 == 0) {
    #pragma unroll
    for (int mt = 0; mt < 4; ++mt) {
      reds[w][mt*16 + l15] = sP[mt];
      reds2[w][mt*16 + l15] = s2P[mt];
    }
  }
  __syncthreads();
  if (tid < 64) {
    float s = reds[0][tid] + reds[1][tid] + reds[2][tid] + reds[3][tid];
    float s2 = reds2[0][tid] + reds2[1][tid] + reds2[2][tid] + reds2[3][tid];
    float m = s * (1.f/128.f);
    float var = s2 * (1.f/128.f) - m*m;
    mv[tid][0] = m;
    mv[tid][1] = rsqrtf(var + 1e-5f);
  }
  __syncthreads();

  float4 gv[2], bv2[2];
  #pragma unroll
  for (int dt = 0; dt < 2; ++dt) {
    gv[dt]  = *(const float4*)&g1[w*32 + dt*16 + l4*4];
    bv2[dt] = *(const float4*)&b1n[w*32 + dt*16 + l4*4];
  }
  #pragma unroll
  for (int mt = 0; mt < 4; ++mt) {
    int row = mt*16 + l15;
    float m = mv[row][0], inv = mv[row][1];
    float lg[8];
    #pragma unroll
    for (int e = 0; e < 8; ++e) lg[e] = 0.f;
    #pragma unroll
    for (int dt = 0; dt < 2; ++dt) {
      int dim = w*32 + dt*16 + l4*4;
      f32x4 r = y[dt][mt];
      float o0 = (r[0]-m)*inv*((float*)&gv[dt])[0] + ((float*)&bv2[dt])[0];
      float o1 = (r[1]-m)*inv*((float*)&gv[dt])[1] + ((float*)&bv2[dt])[1];
      float o2 = (r[2]-m)*inv*((float*)&gv[dt])[2] + ((float*)&bv2[dt])[2];
      float o3 = (r[3]-m)*inv*((float*)&gv[dt])[3] + ((float*)&bv2[dt])[3];
      float4 ov; ov.x = o0; ov.y = o1; ov.z = o2; ov.w = o3;
      *(float4*)&out1[(size_t)(t0 + row) * Dd + dim] = ov;
      uint2 p; p.x = pack2bf(o0, o1); p.y = pack2bf(o2, o3);
      *(uint2*)&out1b[(size_t)(t0 + row) * Dd + dim] = p;
      #pragma unroll
      for (int e = 0; e < 8; ++e)
        lg[e] += o0*wgs[(dim+0)*8+e] + o1*wgs[(dim+1)*8+e]
               + o2*wgs[(dim+2)*8+e] + o3*wgs[(dim+3)*8+e];
    }
    #pragma unroll
    for (int e = 0; e < 8; ++e) {
      lg[e] += __shfl_xor(lg[e], 16, 64);
      lg[e] += __shfl_xor(lg[e], 32, 64);
    }
    if (l4 == 0) {
      #pragma unroll
      for (int e = 0; e < 8; ++e) atomicAdd(&lgs[row*8 + e], lg[e]);
    }
  }
  __syncthreads();

  int i0 = 0, i1 = -1, p0 = 0, p1 = 0;
  float g0 = 0.f, gg1 = 0.f;
  if (tid < 64) {
    float lgv[8];
    #pragma unroll
    for (int e = 0; e < 8; ++e) lgv[e] = lgs[tid*8 + e];
    float v0 = lgv[0];
    #pragma unroll
    for (int e = 1; e < 8; ++e) if (lgv[e] > v0) { v0 = lgv[e]; i0 = e; }
    float v1 = -INFINITY;
    #pragma unroll
    for (int e = 0; e < 8; ++e) if (e != i0 && lgv[e] > v1) { v1 = lgv[e]; i1 = e; }
    g0 = 1.f / (1.f + __expf(v1 - v0));
    gg1 = 1.f - g0;
    atomicAdd(&s_imp[i0], g0);  atomicAdd(&s_imp[i1], gg1);
    atomicAdd(&s_load[i0], 1.f); atomicAdd(&s_load[i1], 1.f);
    p0 = atomicAdd(&s_cnt[i0], 1);
    p1 = atomicAdd(&s_cnt[i1], 1);
  }
  __syncthreads();
  if (tid < 8) {
    s_base[tid] = atomicAdd(&cnt[tid], s_cnt[tid]);
    atomicAdd(&imp[tid], s_imp[tid]);
    atomicAdd(&loadv[tid], s_load[tid]);
  }
  __syncthreads();
  if (tid < 64) {
    int t = t0 + tid;
    int o0 = i0 * Tt + s_base[i0] + p0;
    etok[o0] = t;               egate[o0] = g0;
    int o1 = i1 * Tt + s_base[i1] + p1;
    etok[o1] = t | (1 << 30);   egate[o1] = gg1;
  }
}

// ---------------- K6: grouped sparse MoE FFN (MFMA bf16, bf16 in/out) ----------------
__global__ __launch_bounds__(256) void moe_kernel(const short* __restrict__ out1b,
    const short* __restrict__ W1t, const float* __restrict__ b1,
    const short* __restrict__ W2t, const float* __restrict__ b2,
    const int* __restrict__ cnt, const int* __restrict__ etok, const float* __restrict__ egate,
    short* __restrict__ moe0, short* __restrict__ moe1)
{
  __shared__ short xs[64][136];
  __shared__ short hs[64][136];
  __shared__ int els[64];
  __shared__ float gls[64];

  const int e = blockIdx.y;
  const int count = cnt[e];
  const int t0 = blockIdx.x * 64;
  if (t0 >= count) return;
  const int nt = min(64, count - t0);
  const int tid = threadIdx.x;

  if (tid < 64) {
    int idx = (tid < nt) ? tid : 0;
    els[tid] = etok[e * Tt + t0 + idx];
    gls[tid] = (tid < nt) ? egate[e * Tt + t0 + tid] : 0.f;
  }
  __syncthreads();

  #pragma unroll
  for (int it = 0; it < 8; ++it) {
    int lin = it * 256 + tid;
    int r = lin >> 5;
    int c4 = (lin & 31) << 2;
    int tok = els[r] & 0x3FFFFFFF;
    *(uint2*)&xs[r][c4] = *(const uint2*)&out1b[(size_t)tok * Dd + c4];
  }
  __syncthreads();

  const int lane = tid & 63;
  const int w = tid >> 6;
  const int l15 = lane & 15;
  const int l4 = lane >> 4;

  f32x4 zero4 = {0.f, 0.f, 0.f, 0.f};
  f32x4 y[2][4];
  #pragma unroll
  for (int dt = 0; dt < 2; ++dt)
    #pragma unroll
    for (int mt = 0; mt < 4; ++mt) y[dt][mt] = zero4;

  const short* W1p = W1t + (size_t)e * FFd * Dd;
  const short* W2p = W2t + (size_t)e * Dd * FFd;

  for (int ch = 0; ch < 4; ++ch) {
    f32x4 h[2][4];
    #pragma unroll
    for (int ft = 0; ft < 2; ++ft)
      #pragma unroll
      for (int mt = 0; mt < 4; ++mt) h[ft][mt] = zero4;

    #pragma unroll
    for (int kt = 0; kt < 4; ++kt) {
      bf16x8 a0 = *(const bf16x8*)&W1p[(size_t)(ch*128 + w*32 + 0*16 + l15) * Dd + kt*32 + l4*8];
      bf16x8 a1 = *(const bf16x8*)&W1p[(size_t)(ch*128 + w*32 + 1*16 + l15) * Dd + kt*32 + l4*8];
      bf16x8 bm[4];
      #pragma unroll
      for (int mt = 0; mt < 4; ++mt)
        bm[mt] = *(const bf16x8*)&xs[mt*16 + l15][kt*32 + l4*8];
      #pragma unroll
      for (int mt = 0; mt < 4; ++mt) {
        h[0][mt] = __builtin_amdgcn_mfma_f32_16x16x32_bf16(a0, bm[mt], h[0][mt], 0, 0, 0);
        h[1][mt] = __builtin_amdgcn_mfma_f32_16x16x32_bf16(a1, bm[mt], h[1][mt], 0, 0, 0);
      }
    }

    float4 b1v0 = *(const float4*)&b1[e*FFd + ch*128 + w*32 + 0*16 + l4*4];
    float4 b1v1 = *(const float4*)&b1[e*FFd + ch*128 + w*32 + 1*16 + l4*4];
    __syncthreads();
    #pragma unroll
    for (int mt = 0; mt < 4; ++mt) {
      uint2 p0, p1;
      p0.x = pack2bf(fmaxf(h[0][mt][0] + b1v0.x, 0.f), fmaxf(h[0][mt][1] + b1v0.y, 0.f));
      p0.y = pack2bf(fmaxf(h[0][mt][2] + b1v0.z, 0.f), fmaxf(h[0][mt][3] + b1v0.w, 0.f));
      *(uint2*)&hs[mt*16 + l15][w*32 + 0*16 + l4*4] = p0;
      p1.x = pack2bf(fmaxf(h[1][mt][0] + b1v1.x, 0.f), fmaxf(h[1][mt][1] + b1v1.y, 0.f));
      p1.y = pack2bf(fmaxf(h[1][mt][2] + b1v1.z, 0.f), fmaxf(h[1][mt][3] + b1v1.w, 0.f));
      *(uint2*)&hs[mt*16 + l15][w*32 + 1*16 + l4*4] = p1;
    }
    __syncthreads();

    #pragma unroll
    for (int kt = 0; kt < 4; ++kt) {
      bf16x8 a0 = *(const bf16x8*)&W2p[(size_t)(w*32 + 0*16 + l15) * FFd + ch*128 + kt*32 + l4*8];
      bf16x8 a1 = *(const bf16x8*)&W2p[(size_t)(w*32 + 1*16 + l15) * FFd + ch*128 + kt*32 + l4*8];
      bf16x8 bm[4];
      #pragma unroll
      for (int mt = 0; mt < 4; ++mt)
        bm[mt] = *(const bf16x8*)&hs[mt*16 + l15][kt*32 + l4*8];
      #pragma unroll
      for (int mt = 0; mt < 4; ++mt) {
        y[0][mt] = __builtin_amdgcn_mfma_f32_16x16x32_bf16(a0, bm[mt], y[0][mt], 0, 0, 0);
        y[1][mt] = __builtin_amdgcn_mfma_f32_16x16x32_bf16(a1, bm[mt], y[1][mt], 0, 0, 0);
      }
    }
  }

  float4 b2v[2];
  b2v[0] = *(const float4*)&b2[e*Dd + w*32 + 0*16 + l4*4];
  b2v[1] = *(const float4*)&b2[e*Dd + w*32 + 1*16 + l4*4];
  #pragma unroll
  for (int mt = 0; mt < 4; ++mt) {
    int m = mt*16 + l15;
    if (m < nt) {
      int raw = els[m];
      int t = raw & 0x3FFFFFFF;
      float g = gls[m];
      short* basep = (raw & (1 << 30)) ? moe1 : moe0;
      #pragma unroll
      for (int dt = 0; dt < 2; ++dt) {
        float v0 = g * (y[dt][mt][0] + ((dt == 0) ? b2v[0].x : b2v[1].x));
        float v1 = g * (y[dt][mt][1] + ((dt == 0) ? b2v[0].y : b2v[1].y));
        float v2 = g * (y[dt][mt][2] + ((dt == 0) ? b2v[0].z : b2v[1].z));
        float v3 = g * (y[dt][mt][3] + ((dt == 0) ? b2v[0].w : b2v[1].w));
        uint2 p; p.x = pack2bf(v0, v1); p.y = pack2bf(v2, v3);
        *(uint2*)&basep[(size_t)t * Dd + w*32 + dt*16 + l4*4] = p;
      }
    }
  }
}

// ---------------- K7: residual + LN2 -> d_out (+ loss in block 0) ----------------
// grid 3200, block 256 (one wave per token; no LDS).
__global__ __launch_bounds__(256) void ln2_kernel(const float* __restrict__ out1,
    const short* __restrict__ moe0, const short* __restrict__ moe1,
    const float* __restrict__ g, const float* __restrict__ bb,
    const float* __restrict__ imp, const float* __restrict__ loadv,
    float* __restrict__ out, float* __restrict__ out_loss)
{
  const int tid = threadIdx.x;
  const int lane = tid & 63;
  const int t = blockIdx.x * 4 + (tid >> 6);
  const int j = lane * 2;

  float2 xv = *(const float2*)&out1[(size_t)t * Dd + j];
  unsigned m0 = *(const unsigned*)&moe0[(size_t)t * Dd + j];
  unsigned m1 = *(const unsigned*)&moe1[(size_t)t * Dd + j];
  union { unsigned u; float f; } a, b, c, d;
  a.u = m0 << 16; b.u = m0 & 0xFFFF0000u;
  c.u = m1 << 16; d.u = m1 & 0xFFFF0000u;
  float r0 = xv.x + a.f + c.f;
  float r1 = xv.y + b.f + d.f;

  float s = r0 + r1;
  float s2 = r0*r0 + r1*r1;
  #pragma unroll
  for (int off = 32; off > 0; off >>= 1) {
    s  += __shfl_xor(s, off, 64);
    s2 += __shfl_xor(s2, off, 64);
  }
  float mean = s * (1.f/128.f);
  float var = s2 * (1.f/128.f) - mean*mean;
  float inv = rsqrtf(var + 1e-5f);
  float2 ov;
  ov.x = (r0 - mean) * inv * g[j]   + bb[j];
  ov.y = (r1 - mean) * inv * g[j+1] + bb[j+1];
  *(float2*)&out[(size_t)t * Dd + j] = ov;

  if (blockIdx.x == 0 && tid == 0) {
    float m1s = 0.f;
    for (int e = 0; e < 8; ++e) m1s += imp[e];
    m1s *= 0.125f;
    float v1 = 0.f;
    for (int e = 0; e < 8; ++e) { float dd = imp[e] - m1s; v1 += dd * dd; }
    v1 *= 0.125f;
    float c1 = v1 / (m1s * m1s + 1e-10f);
    float m2 = 0.f;
    for (int e = 0; e < 8; ++e) m2 += loadv[e];
    m2 *= 0.125f;
    float v2 = 0.f;
    for (int e = 0; e < 8; ++e) { float dd = loadv[e] - m2; v2 += dd * dd; }
    v2 *= 0.125f;
    float c2 = v2 / (m2 * m2 + 1e-10f);
    out_loss[0] = (c1 + c2) * 0.01f;
  }
}

extern "C" void kernel_launch(void* const* d_in, const int* in_sizes, int n_in,
                              void* d_out, int out_size, void* d_ws, size_t ws_size,
                              hipStream_t stream)
{
  (void)in_sizes; (void)n_in; (void)out_size; (void)ws_size;
  const float* x      = (const float*)d_in[0];
  const float* Wq     = (const float*)d_in[1];
  const float* Wk     = (const float*)d_in[2];
  const float* Wv     = (const float*)d_in[3];
  const float* Wo     = (const float*)d_in[4];
  const float* bo     = (const float*)d_in[5];
  const float* ln1_g  = (const float*)d_in[6];
  const float* ln1_b  = (const float*)d_in[7];
  const float* w_gate = (const float*)d_in[8];
  const float* W1     = (const float*)d_in[9];
  const float* b1     = (const float*)d_in[10];
  const float* W2     = (const float*)d_in[11];
  const float* b2     = (const float*)d_in[12];
  const float* ln2_g  = (const float*)d_in[13];
  const float* ln2_b  = (const float*)d_in[14];

  char* wsb = (char*)d_ws;
  size_t off = 0;
  short* attn_b  = (short*)(wsb + off); off += (size_t)Tt*Dd*2;          //  3,276,800
  float* out1    = (float*)(wsb + off); off += (size_t)Tt*Dd*4;          //  6,553,600
  short* out1b   = (short*)(wsb + off); off += (size_t)Tt*Dd*2;          //  3,276,800
  short* moe0    = (short*)(wsb + off); off += (size_t)Tt*Dd*2;          //  3,276,800
  short* moe1    = (short*)(wsb + off); off += (size_t)Tt*Dd*2;          //  3,276,800
  short* q_bf    = (short*)(wsb + off); off += (size_t)256*400*16*2;     //  3,276,800
  short* k_bf    = (short*)(wsb + off); off += (size_t)256*400*16*2;     //  3,276,800
  short* v_bf    = (short*)(wsb + off); off += (size_t)256*400*16*2;     //  3,276,800
  short* W1t     = (short*)(wsb + off); off += (size_t)Ee*FFd*Dd*2;      //  1,048,576
  short* W2t     = (short*)(wsb + off); off += (size_t)Ee*FFd*Dd*2;      //  1,048,576
  short* wo_t    = (short*)(wsb + off); off += (size_t)Dd*Dd*2;          //     32,768
  short* qkvw    = (short*)(wsb + off); off += (size_t)384*Dd*2;         //     98,304
  int*   gmeta   = (int*)(wsb + off);   off += 256;
  int*   etok    = (int*)(wsb + off);   off += (size_t)Ee*Tt*4;          //    409,600
  float* egate   = (float*)(wsb + off); off += (size_t)Ee*Tt*4;          //    409,600

  int*   cnt   = gmeta;
  float* imp   = (float*)(gmeta + 8);
  float* loadv = (float*)(gmeta + 16);

  float* out3 = (float*)d_out;
  float* loss = out3 + Tt * Dd;

  prep_kernel<<<1088, 256, 0, stream>>>(W1, W2, Wo, Wq, Wk, Wv, W1t, W2t, wo_t, qkvw, gmeta);
  qkv_kernel<<<200, 256, 0, stream>>>(x, qkvw, q_bf, k_bf, v_bf);
  attn_kernel<<<256, 512, 0, stream>>>(q_bf, k_bf, v_bf, attn_b);
  proj_ln1_gate_kernel<<<200, 256, 0, stream>>>(x, attn_b, wo_t, bo, ln1_g, ln1_b, w_gate,
                                                out1, out1b, cnt, imp, loadv, etok, egate);
  moe_kernel<<<dim3(200, 8), 256, 0, stream>>>(out1b, W1t, b1, W2t, b2, cnt, etok, egate, moe0, moe1);
  ln2_kernel<<<3200, 256, 0, stream>>>(out1, moe0, moe1, ln2_g, ln2_b, imp, loadv, out3, loss);
}

// Round 12
// 101.619 us; speedup vs baseline: 1.2168x; 1.1296x over previous
//
#include <hip/hip_runtime.h>
#include <hip/hip_bf16.h>
#include <math.h>

#define Bb 32
#define Nn 400
#define Dd 128
#define Hh 8
#define QKd 16
#define FFd 512
#define Ee 8
#define Tt (Bb*Nn)   // 12800
#define KPAD 434     // VT row stride (bf16): 217 dwords (odd) -> conflict-free PV reads (R10: 589K conflicts at 424)
#define PP2 34       // P row stride (bf16 elems)

typedef __attribute__((ext_vector_type(8))) __bf16 bf16x8;
typedef __attribute__((ext_vector_type(4))) float f32x4;

#if defined(__has_builtin)
#if __has_builtin(__builtin_amdgcn_exp2f)
#define EXP2(x) __builtin_amdgcn_exp2f(x)
#endif
#endif
#ifndef EXP2
#define EXP2(x) __expf((x) * 0.69314718f)
#endif

// RNE f32->bf16 via HW cvt (compiler emits v_cvt_pk_bf16_f32 for pairs).
__device__ __forceinline__ unsigned short f2bfu(float f){
  union { __hip_bfloat16 h; unsigned short u; } v;
  v.h = __float2bfloat16(f);
  return v.u;
}
__device__ __forceinline__ short f2bf(float f){ return (short)f2bfu(f); }
__device__ __forceinline__ unsigned pack2bf(float a, float b){
  return (unsigned)f2bfu(a) | ((unsigned)f2bfu(b) << 16);
}
__device__ __forceinline__ bf16x8 zero_bf16x8(){
  union { uint4 u; bf16x8 b; } z;
  z.u.x = 0u; z.u.y = 0u; z.u.z = 0u; z.u.w = 0u;
  return z.b;
}

// ---------------- K0: prep — all weight transposes (f32 -> bf16^T) + zero gate meta ----------------
__global__ __launch_bounds__(256) void prep_kernel(
    const float* __restrict__ W1, const float* __restrict__ W2, const float* __restrict__ Wo,
    const float* __restrict__ Wq, const float* __restrict__ Wk, const float* __restrict__ Wv,
    short* __restrict__ W1t, short* __restrict__ W2t, short* __restrict__ wo_t,
    short* __restrict__ qkvw, int* __restrict__ gmeta)
{
  const int bid = blockIdx.x;
  if (bid == 0 && threadIdx.x < 24) gmeta[threadIdx.x] = 0;   // cnt[8], imp[8], loadv[8]

  const float* in; short* out; int C, tile;
  if (bid < 512)        { int e = bid >> 6;         tile = bid & 63;          in = W1 + e*65536; out = W1t + e*65536; C = 512; }
  else if (bid < 1024)  { int e = (bid - 512) >> 6; tile = (bid - 512) & 63;  in = W2 + e*65536; out = W2t + e*65536; C = 128; }
  else if (bid < 1040)  { tile = bid - 1024; in = Wo; out = wo_t;          C = 128; }
  else if (bid < 1056)  { tile = bid - 1040; in = Wq; out = qkvw;          C = 128; }
  else if (bid < 1072)  { tile = bid - 1056; in = Wk; out = qkvw + 16384;  C = 128; }
  else                  { tile = bid - 1072; in = Wv; out = qkvw + 32768;  C = 128; }
  const int R = (bid < 512) ? 128 : (bid < 1024 ? 512 : 128);

  __shared__ float t32[32][33];
  const int nCt = C >> 5;
  const int c0 = (tile % nCt) << 5;
  const int r0 = (tile / nCt) << 5;
  const int tx = threadIdx.x & 31, ty = threadIdx.x >> 5;
  #pragma unroll
  for (int i = 0; i < 4; ++i)
    t32[ty + 8*i][tx] = in[(size_t)(r0 + ty + 8*i) * C + c0 + tx];
  __syncthreads();
  #pragma unroll
  for (int i = 0; i < 4; ++i)
    out[(size_t)(c0 + ty + 8*i) * R + r0 + tx] = f2bf(t32[tx][ty + 8*i]);
}

// ---------------- K1: QKV projection via MFMA, split-bf16 activations ----------------
// grid 200, block 256. qkvw: [384][128] bf16. Outputs q,k,v all [BH][400][16] bf16 (q pre-scaled).
__global__ __launch_bounds__(256) void qkv_kernel(const float* __restrict__ x,
    const short* __restrict__ qkvw,
    short* __restrict__ q, short* __restrict__ k, short* __restrict__ v)
{
  __shared__ short xsh[64][136];
  __shared__ short xsl[64][136];
  const int tid = threadIdx.x;
  const int t0 = blockIdx.x * 64;

  #pragma unroll
  for (int it = 0; it < 8; ++it) {
    int lin = it * 256 + tid;
    int r = lin >> 5;
    int c4 = (lin & 31) << 2;
    float4 xv = *(const float4*)&x[(size_t)(t0 + r) * Dd + c4];
    unsigned h01 = pack2bf(xv.x, xv.y);
    unsigned h23 = pack2bf(xv.z, xv.w);
    union { unsigned u; float f; } ua, ub, uc, ud;
    ua.u = h01 << 16; ub.u = h01 & 0xFFFF0000u;
    uc.u = h23 << 16; ud.u = h23 & 0xFFFF0000u;
    unsigned l01 = pack2bf(xv.x - ua.f, xv.y - ub.f);
    unsigned l23 = pack2bf(xv.z - uc.f, xv.w - ud.f);
    uint2 ph; ph.x = h01; ph.y = h23;
    uint2 pl; pl.x = l01; pl.y = l23;
    *(uint2*)&xsh[r][c4] = ph;
    *(uint2*)&xsl[r][c4] = pl;
  }
  __syncthreads();

  const int lane = tid & 63, w = tid >> 6;
  const int l15 = lane & 15, l4 = lane >> 4;

  f32x4 zero4 = {0.f, 0.f, 0.f, 0.f};
  f32x4 acc[6][4];
  #pragma unroll
  for (int ot = 0; ot < 6; ++ot)
    #pragma unroll
    for (int mt = 0; mt < 4; ++mt) acc[ot][mt] = zero4;

  #pragma unroll
  for (int kt = 0; kt < 4; ++kt) {
    bf16x8 bmh[4], bml[4];
    #pragma unroll
    for (int mt = 0; mt < 4; ++mt) {
      bmh[mt] = *(const bf16x8*)&xsh[mt*16 + l15][kt*32 + l4*8];
      bml[mt] = *(const bf16x8*)&xsl[mt*16 + l15][kt*32 + l4*8];
    }
    #pragma unroll
    for (int ot = 0; ot < 6; ++ot) {
      bf16x8 a = *(const bf16x8*)&qkvw[(size_t)(w*96 + ot*16 + l15) * Dd + kt*32 + l4*8];
      #pragma unroll
      for (int mt = 0; mt < 4; ++mt) {
        acc[ot][mt] = __builtin_amdgcn_mfma_f32_16x16x32_bf16(a, bmh[mt], acc[ot][mt], 0, 0, 0);
        acc[ot][mt] = __builtin_amdgcn_mfma_f32_16x16x32_bf16(a, bml[mt], acc[ot][mt], 0, 0, 0);
      }
    }
  }

  #pragma unroll
  for (int ot = 0; ot < 6; ++ot) {
    const int ob = w*96 + ot*16;
    const int sel = ob >> 7;
    const int hz = (ob & 127) >> 4;
    #pragma unroll
    for (int mt = 0; mt < 4; ++mt) {
      int t = t0 + mt*16 + l15;
      int b = t / Nn, n = t - b * Nn;
      size_t bhn = (size_t)(b*Hh + hz) * Nn + n;
      f32x4 a = acc[ot][mt];
      uint2 p;
      if (sel == 0) {
        p.x = pack2bf(a[0]*0.36067376f, a[1]*0.36067376f);  // 0.25*log2(e)
        p.y = pack2bf(a[2]*0.36067376f, a[3]*0.36067376f);
        *(uint2*)&q[bhn*16 + l4*4] = p;
      } else if (sel == 1) {
        p.x = pack2bf(a[0], a[1]);
        p.y = pack2bf(a[2], a[3]);
        *(uint2*)&k[bhn*16 + l4*4] = p;
      } else {
        p.x = pack2bf(a[0], a[1]);
        p.y = pack2bf(a[2], a[3]);
        *(uint2*)&v[bhn*16 + l4*4] = p;
      }
    }
  }
}

// ---------------- K2: attention via MFMA, one block per bh (bf16 out) ----------------
// grid 256, block 512 (8 waves). Wave w owns q-tiles {w, w+8, w+16, w+24} (<25).
__global__ __launch_bounds__(512) void attn_kernel(const short* __restrict__ q,
    const short* __restrict__ k, const short* __restrict__ v, short* __restrict__ attn_b)
{
  __shared__ short VT[16 * KPAD];        // 13888 B
  __shared__ short P[8][4][16 * PP2];    // 34816 B
  const int tid = threadIdx.x;
  const int bh = blockIdx.x;

  {
    const unsigned* vg = (const unsigned*)(v + (size_t)bh * 400 * 16);
    #pragma unroll
    for (int it = 0; it < 7; ++it) {
      int lin = it*512 + tid;
      if (lin < 3200) {
        int key = lin >> 3, dp = lin & 7;
        unsigned pv = vg[key*8 + dp];
        VT[(2*dp)  * KPAD + key] = (short)(pv & 0xffffu);
        VT[(2*dp+1)* KPAD + key] = (short)(pv >> 16);
      }
    }
    if (tid < 256) {   // zero pad keys 400..415
      int d = tid >> 4, key = 400 + (tid & 15);
      VT[d*KPAD + key] = 0;
    }
  }
  __syncthreads();

  const int w = tid >> 6, lane = tid & 63;
  const int l15 = lane & 15, g = lane >> 4;

  f32x4 zero4 = {0.f, 0.f, 0.f, 0.f};
  f32x4 o[4];
  float lsum[4];
  bf16x8 qf[4];
  #pragma unroll
  for (int i = 0; i < 4; ++i) {
    o[i] = zero4; lsum[i] = 0.f;
    int qt = w + 8*i;
    if (qt < 25 && g < 2)
      qf[i] = *(const bf16x8*)&q[((size_t)bh*400 + qt*16 + l15)*16 + 8*g];
    else
      qf[i] = zero_bf16x8();
  }

  #pragma unroll
  for (int cc = 0; cc < 13; ++cc) {
    #pragma unroll
    for (int sub = 0; sub < 2; ++sub) {
      const int kt = cc*2 + sub;
      if (kt < 25) {
        bf16x8 kf;
        if (g < 2) kf = *(const bf16x8*)&k[((size_t)bh*400 + kt*16 + l15)*16 + 8*g];
        else       kf = zero_bf16x8();
        #pragma unroll
        for (int i = 0; i < 4; ++i) {
          int qt = w + 8*i;
          if (qt < 25) {
            f32x4 s = __builtin_amdgcn_mfma_f32_16x16x32_bf16(kf, qf[i], zero4, 0, 0, 0);
            float p0 = EXP2(s[0]);
            float p1 = EXP2(s[1]);
            float p2 = EXP2(s[2]);
            float p3 = EXP2(s[3]);
            lsum[i] += (p0 + p1) + (p2 + p3);
            uint2 pk;
            pk.x = pack2bf(p0, p1);
            pk.y = pack2bf(p2, p3);
            *(uint2*)&P[w][i][l15*PP2 + sub*16 + 4*g] = pk;
          }
        }
      } else {   // kt == 25: keys 400..415 -> P = 0
        uint2 z; z.x = 0u; z.y = 0u;
        #pragma unroll
        for (int i = 0; i < 4; ++i) {
          int qt = w + 8*i;
          if (qt < 25) *(uint2*)&P[w][i][l15*PP2 + sub*16 + 4*g] = z;
        }
      }
    }
    bf16x8 vf = *(const bf16x8*)&VT[l15*KPAD + cc*32 + 8*g];
    #pragma unroll
    for (int i = 0; i < 4; ++i) {
      int qt = w + 8*i;
      if (qt < 25) {
        bf16x8 pf = *(const bf16x8*)&P[w][i][l15*PP2 + 8*g];
        o[i] = __builtin_amdgcn_mfma_f32_16x16x32_bf16(vf, pf, o[i], 0, 0, 0);
      }
    }
  }

  const int b = bh >> 3, h = bh & 7;
  #pragma unroll
  for (int i = 0; i < 4; ++i) {
    int qt = w + 8*i;
    if (qt < 25) {
      float ls = lsum[i];
      ls += __shfl_xor(ls, 16, 64);
      ls += __shfl_xor(ls, 32, 64);
      float inv = 1.f / ls;
      uint2 pk;
      pk.x = pack2bf(o[i][0]*inv, o[i][1]*inv);
      pk.y = pack2bf(o[i][2]*inv, o[i][3]*inv);
      *(uint2*)&attn_b[((size_t)b*Nn + qt*16 + l15)*Dd + h*16 + 4*g] = pk;
    }
  }
}

// ---------------- K3: output proj (MFMA) + residual + LN1 + gating, fused ----------------
// grid 200, block 256 (4 waves x 32 outdims; 64 tokens/block).
__global__ __launch_bounds__(256) void proj_ln1_gate_kernel(
    const float* __restrict__ x, const short* __restrict__ attn_b,
    const short* __restrict__ wo_t, const float* __restrict__ bo,
    const float* __restrict__ g1, const float* __restrict__ b1n,
    const float* __restrict__ w_gate,
    float* __restrict__ out1, short* __restrict__ out1b,
    int* __restrict__ cnt, float* __restrict__ imp, float* __restrict__ loadv,
    int* __restrict__ etok, float* __restrict__ egate)
{
  __shared__ short as_[64][136];
  __shared__ float reds[4][64];
  __shared__ float reds2[4][64];
  __shared__ float mv[64][2];
  __shared__ float lgs[64*8];
  __shared__ float wgs[128*8];
  __shared__ float s_imp[8], s_load[8];
  __shared__ int s_cnt[8], s_base[8];

  const int tid = threadIdx.x;
  const int t0 = blockIdx.x * 64;

  #pragma unroll
  for (int it = 0; it < 8; ++it) {
    int lin = it * 256 + tid;
    int r = lin >> 5;
    int c4 = (lin & 31) << 2;
    *(uint2*)&as_[r][c4] = *(const uint2*)&attn_b[(size_t)(t0 + r) * Dd + c4];
  }
  #pragma unroll
  for (int it = 0; it < 4; ++it) wgs[it*256 + tid] = w_gate[it*256 + tid];
  lgs[tid] = 0.f; lgs[tid + 256] = 0.f;
  if (tid < 8) { s_imp[tid] = 0.f; s_load[tid] = 0.f; s_cnt[tid] = 0; }
  __syncthreads();

  const int lane = tid & 63, w = tid >> 6;
  const int l15 = lane & 15, l4 = lane >> 4;

  f32x4 zero4 = {0.f, 0.f, 0.f, 0.f};
  f32x4 y[2][4];
  #pragma unroll
  for (int dt = 0; dt < 2; ++dt)
    #pragma unroll
    for (int mt = 0; mt < 4; ++mt) y[dt][mt] = zero4;

  #pragma unroll
  for (int kt = 0; kt < 4; ++kt) {
    bf16x8 a0 = *(const bf16x8*)&wo_t[(size_t)(w*32 + l15) * Dd + kt*32 + l4*8];
    bf16x8 a1 = *(const bf16x8*)&wo_t[(size_t)(w*32 + 16 + l15) * Dd + kt*32 + l4*8];
    bf16x8 bm[4];
    #pragma unroll
    for (int mt = 0; mt < 4; ++mt)
      bm[mt] = *(const bf16x8*)&as_[mt*16 + l15][kt*32 + l4*8];
    #pragma unroll
    for (int mt = 0; mt < 4; ++mt) {
      y[0][mt] = __builtin_amdgcn_mfma_f32_16x16x32_bf16(a0, bm[mt], y[0][mt], 0, 0, 0);
      y[1][mt] = __builtin_amdgcn_mfma_f32_16x16x32_bf16(a1, bm[mt], y[1][mt], 0, 0, 0);
    }
  }

  float4 bov[2];
  bov[0] = *(const float4*)&bo[w*32 + 0*16 + l4*4];
  bov[1] = *(const float4*)&bo[w*32 + 1*16 + l4*4];
  float sP[4], s2P[4];
  #pragma unroll
  for (int mt = 0; mt < 4; ++mt) { sP[mt] = 0.f; s2P[mt] = 0.f; }
  #pragma unroll
  for (int mt = 0; mt < 4; ++mt) {
    int row = mt*16 + l15;
    #pragma unroll
    for (int dt = 0; dt < 2; ++dt) {
      int dim = w*32 + dt*16 + l4*4;
      float4 xv = *(const float4*)&x[(size_t)(t0 + row) * Dd + dim];
      float4 bv = bov[dt];
      f32x4 r = y[dt][mt];
      r[0] += bv.x + xv.x; r[1] += bv.y + xv.y;
      r[2] += bv.z + xv.z; r[3] += bv.w + xv.w;
      y[dt][mt] = r;
      sP[mt]  += (r[0] + r[1]) + (r[2] + r[3]);
      s2P[mt] += (r[0]*r[0] + r[1]*r[1]) + (r[2]*r[2] + r[3]*r[3]);
    }
  }
  #pragma unroll
  for (int mt = 0; mt < 4; ++mt) {
    sP[mt]  += __shfl_xor(sP[mt], 16, 64);  sP[mt]  += __shfl_xor(sP[mt], 32, 64);
    s2P[mt] += __shfl_xor(s2P[mt], 16, 64); s2P[mt] += __shfl_xor(s2P[mt], 32, 64);
  }
  if (l4 == 0) {
    #pragma unroll
    for (int mt = 0; mt < 4; ++mt) {
      reds[w][mt*16 + l15] = sP[mt];
      reds2[w][mt*16 + l15] = s2P[mt];
    }
  }
  __syncthreads();
  if (tid < 64) {
    float s = reds[0][tid] + reds[1][tid] + reds[2][tid] + reds[3][tid];
    float s2 = reds2[0][tid] + reds2[1][tid] + reds2[2][tid] + reds2[3][tid];
    float m = s * (1.f/128.f);
    float var = s2 * (1.f/128.f) - m*m;
    mv[tid][0] = m;
    mv[tid][1] = rsqrtf(var + 1e-5f);
  }
  __syncthreads();

  float4 gv[2], bv2[2];
  #pragma unroll
  for (int dt = 0; dt < 2; ++dt) {
    gv[dt]  = *(const float4*)&g1[w*32 + dt*16 + l4*4];
    bv2[dt] = *(const float4*)&b1n[w*32 + dt*16 + l4*4];
  }
  #pragma unroll
  for (int mt = 0; mt < 4; ++mt) {
    int row = mt*16 + l15;
    float m = mv[row][0], inv = mv[row][1];
    float lg[8];
    #pragma unroll
    for (int e = 0; e < 8; ++e) lg[e] = 0.f;
    #pragma unroll
    for (int dt = 0; dt < 2; ++dt) {
      int dim = w*32 + dt*16 + l4*4;
      f32x4 r = y[dt][mt];
      float o0 = (r[0]-m)*inv*((float*)&gv[dt])[0] + ((float*)&bv2[dt])[0];
      float o1 = (r[1]-m)*inv*((float*)&gv[dt])[1] + ((float*)&bv2[dt])[1];
      float o2 = (r[2]-m)*inv*((float*)&gv[dt])[2] + ((float*)&bv2[dt])[2];
      float o3 = (r[3]-m)*inv*((float*)&gv[dt])[3] + ((float*)&bv2[dt])[3];
      float4 ov; ov.x = o0; ov.y = o1; ov.z = o2; ov.w = o3;
      *(float4*)&out1[(size_t)(t0 + row) * Dd + dim] = ov;
      uint2 p; p.x = pack2bf(o0, o1); p.y = pack2bf(o2, o3);
      *(uint2*)&out1b[(size_t)(t0 + row) * Dd + dim] = p;
      #pragma unroll
      for (int e = 0; e < 8; ++e)
        lg[e] += o0*wgs[(dim+0)*8+e] + o1*wgs[(dim+1)*8+e]
               + o2*wgs[(dim+2)*8+e] + o3*wgs[(dim+3)*8+e];
    }
    #pragma unroll
    for (int e = 0; e < 8; ++e) {
      lg[e] += __shfl_xor(lg[e], 16, 64);
      lg[e] += __shfl_xor(lg[e], 32, 64);
    }
    if (l4 == 0) {
      #pragma unroll
      for (int e = 0; e < 8; ++e) atomicAdd(&lgs[row*8 + e], lg[e]);
    }
  }
  __syncthreads();

  int i0 = 0, i1 = -1, p0 = 0, p1 = 0;
  float g0 = 0.f, gg1 = 0.f;
  if (tid < 64) {
    float lgv[8];
    #pragma unroll
    for (int e = 0; e < 8; ++e) lgv[e] = lgs[tid*8 + e];
    float v0 = lgv[0];
    #pragma unroll
    for (int e = 1; e < 8; ++e) if (lgv[e] > v0) { v0 = lgv[e]; i0 = e; }
    float v1 = -INFINITY;
    #pragma unroll
    for (int e = 0; e < 8; ++e) if (e != i0 && lgv[e] > v1) { v1 = lgv[e]; i1 = e; }
    g0 = 1.f / (1.f + __expf(v1 - v0));
    gg1 = 1.f - g0;
    atomicAdd(&s_imp[i0], g0);  atomicAdd(&s_imp[i1], gg1);
    atomicAdd(&s_load[i0], 1.f); atomicAdd(&s_load[i1], 1.f);
    p0 = atomicAdd(&s_cnt[i0], 1);
    p1 = atomicAdd(&s_cnt[i1], 1);
  }
  __syncthreads();
  if (tid < 8) {
    s_base[tid] = atomicAdd(&cnt[tid], s_cnt[tid]);
    atomicAdd(&imp[tid], s_imp[tid]);
    atomicAdd(&loadv[tid], s_load[tid]);
  }
  __syncthreads();
  if (tid < 64) {
    int t = t0 + tid;
    int o0 = i0 * Tt + s_base[i0] + p0;
    etok[o0] = t;               egate[o0] = g0;
    int o1 = i1 * Tt + s_base[i1] + p1;
    etok[o1] = t | (1 << 30);   egate[o1] = gg1;
  }
}

// ---------------- K6: grouped sparse MoE FFN (MFMA bf16, bf16 in/out) ----------------
__global__ __launch_bounds__(256) void moe_kernel(const short* __restrict__ out1b,
    const short* __restrict__ W1t, const float* __restrict__ b1,
    const short* __restrict__ W2t, const float* __restrict__ b2,
    const int* __restrict__ cnt, const int* __restrict__ etok, const float* __restrict__ egate,
    short* __restrict__ moe0, short* __restrict__ moe1)
{
  __shared__ short xs[64][136];
  __shared__ short hs[64][136];
  __shared__ int els[64];
  __shared__ float gls[64];

  const int e = blockIdx.y;
  const int count = cnt[e];
  const int t0 = blockIdx.x * 64;
  if (t0 >= count) return;
  const int nt = min(64, count - t0);
  const int tid = threadIdx.x;

  if (tid < 64) {
    int idx = (tid < nt) ? tid : 0;
    els[tid] = etok[e * Tt + t0 + idx];
    gls[tid] = (tid < nt) ? egate[e * Tt + t0 + tid] : 0.f;
  }
  __syncthreads();

  #pragma unroll
  for (int it = 0; it < 8; ++it) {
    int lin = it * 256 + tid;
    int r = lin >> 5;
    int c4 = (lin & 31) << 2;
    int tok = els[r] & 0x3FFFFFFF;
    *(uint2*)&xs[r][c4] = *(const uint2*)&out1b[(size_t)tok * Dd + c4];
  }
  __syncthreads();

  const int lane = tid & 63;
  const int w = tid >> 6;
  const int l15 = lane & 15;
  const int l4 = lane >> 4;

  f32x4 zero4 = {0.f, 0.f, 0.f, 0.f};
  f32x4 y[2][4];
  #pragma unroll
  for (int dt = 0; dt < 2; ++dt)
    #pragma unroll
    for (int mt = 0; mt < 4; ++mt) y[dt][mt] = zero4;

  const short* W1p = W1t + (size_t)e * FFd * Dd;
  const short* W2p = W2t + (size_t)e * Dd * FFd;

  for (int ch = 0; ch < 4; ++ch) {
    f32x4 h[2][4];
    #pragma unroll
    for (int ft = 0; ft < 2; ++ft)
      #pragma unroll
      for (int mt = 0; mt < 4; ++mt) h[ft][mt] = zero4;

    #pragma unroll
    for (int kt = 0; kt < 4; ++kt) {
      bf16x8 a0 = *(const bf16x8*)&W1p[(size_t)(ch*128 + w*32 + 0*16 + l15) * Dd + kt*32 + l4*8];
      bf16x8 a1 = *(const bf16x8*)&W1p[(size_t)(ch*128 + w*32 + 1*16 + l15) * Dd + kt*32 + l4*8];
      bf16x8 bm[4];
      #pragma unroll
      for (int mt = 0; mt < 4; ++mt)
        bm[mt] = *(const bf16x8*)&xs[mt*16 + l15][kt*32 + l4*8];
      #pragma unroll
      for (int mt = 0; mt < 4; ++mt) {
        h[0][mt] = __builtin_amdgcn_mfma_f32_16x16x32_bf16(a0, bm[mt], h[0][mt], 0, 0, 0);
        h[1][mt] = __builtin_amdgcn_mfma_f32_16x16x32_bf16(a1, bm[mt], h[1][mt], 0, 0, 0);
      }
    }

    float4 b1v0 = *(const float4*)&b1[e*FFd + ch*128 + w*32 + 0*16 + l4*4];
    float4 b1v1 = *(const float4*)&b1[e*FFd + ch*128 + w*32 + 1*16 + l4*4];
    __syncthreads();
    #pragma unroll
    for (int mt = 0; mt < 4; ++mt) {
      uint2 p0, p1;
      p0.x = pack2bf(fmaxf(h[0][mt][0] + b1v0.x, 0.f), fmaxf(h[0][mt][1] + b1v0.y, 0.f));
      p0.y = pack2bf(fmaxf(h[0][mt][2] + b1v0.z, 0.f), fmaxf(h[0][mt][3] + b1v0.w, 0.f));
      *(uint2*)&hs[mt*16 + l15][w*32 + 0*16 + l4*4] = p0;
      p1.x = pack2bf(fmaxf(h[1][mt][0] + b1v1.x, 0.f), fmaxf(h[1][mt][1] + b1v1.y, 0.f));
      p1.y = pack2bf(fmaxf(h[1][mt][2] + b1v1.z, 0.f), fmaxf(h[1][mt][3] + b1v1.w, 0.f));
      *(uint2*)&hs[mt*16 + l15][w*32 + 1*16 + l4*4] = p1;
    }
    __syncthreads();

    #pragma unroll
    for (int kt = 0; kt < 4; ++kt) {
      bf16x8 a0 = *(const bf16x8*)&W2p[(size_t)(w*32 + 0*16 + l15) * FFd + ch*128 + kt*32 + l4*8];
      bf16x8 a1 = *(const bf16x8*)&W2p[(size_t)(w*32 + 1*16 + l15) * FFd + ch*128 + kt*32 + l4*8];
      bf16x8 bm[4];
      #pragma unroll
      for (int mt = 0; mt < 4; ++mt)
        bm[mt] = *(const bf16x8*)&hs[mt*16 + l15][kt*32 + l4*8];
      #pragma unroll
      for (int mt = 0; mt < 4; ++mt) {
        y[0][mt] = __builtin_amdgcn_mfma_f32_16x16x32_bf16(a0, bm[mt], y[0][mt], 0, 0, 0);
        y[1][mt] = __builtin_amdgcn_mfma_f32_16x16x32_bf16(a1, bm[mt], y[1][mt], 0, 0, 0);
      }
    }
  }

  float4 b2v[2];
  b2v[0] = *(const float4*)&b2[e*Dd + w*32 + 0*16 + l4*4];
  b2v[1] = *(const float4*)&b2[e*Dd + w*32 + 1*16 + l4*4];
  #pragma unroll
  for (int mt = 0; mt < 4; ++mt) {
    int m = mt*16 + l15;
    if (m < nt) {
      int raw = els[m];
      int t = raw & 0x3FFFFFFF;
      float g = gls[m];
      short* basep = (raw & (1 << 30)) ? moe1 : moe0;
      #pragma unroll
      for (int dt = 0; dt < 2; ++dt) {
        float v0 = g * (y[dt][mt][0] + ((dt == 0) ? b2v[0].x : b2v[1].x));
        float v1 = g * (y[dt][mt][1] + ((dt == 0) ? b2v[0].y : b2v[1].y));
        float v2 = g * (y[dt][mt][2] + ((dt == 0) ? b2v[0].z : b2v[1].z));
        float v3 = g * (y[dt][mt][3] + ((dt == 0) ? b2v[0].w : b2v[1].w));
        uint2 p; p.x = pack2bf(v0, v1); p.y = pack2bf(v2, v3);
        *(uint2*)&basep[(size_t)t * Dd + w*32 + dt*16 + l4*4] = p;
      }
    }
  }
}

// ---------------- K7: residual + LN2 -> d_out (+ loss in block 0) ----------------
// grid 3200, block 256 (one wave per token; no LDS).
__global__ __launch_bounds__(256) void ln2_kernel(const float* __restrict__ out1,
    const short* __restrict__ moe0, const short* __restrict__ moe1,
    const float* __restrict__ g, const float* __restrict__ bb,
    const float* __restrict__ imp, const float* __restrict__ loadv,
    float* __restrict__ out, float* __restrict__ out_loss)
{
  const int tid = threadIdx.x;
  const int lane = tid & 63;
  const int t = blockIdx.x * 4 + (tid >> 6);
  const int j = lane * 2;

  float2 xv = *(const float2*)&out1[(size_t)t * Dd + j];
  unsigned m0 = *(const unsigned*)&moe0[(size_t)t * Dd + j];
  unsigned m1 = *(const unsigned*)&moe1[(size_t)t * Dd + j];
  union { unsigned u; float f; } a, b, c, d;
  a.u = m0 << 16; b.u = m0 & 0xFFFF0000u;
  c.u = m1 << 16; d.u = m1 & 0xFFFF0000u;
  float r0 = xv.x + a.f + c.f;
  float r1 = xv.y + b.f + d.f;

  float s = r0 + r1;
  float s2 = r0*r0 + r1*r1;
  #pragma unroll
  for (int off = 32; off > 0; off >>= 1) {
    s  += __shfl_xor(s, off, 64);
    s2 += __shfl_xor(s2, off, 64);
  }
  float mean = s * (1.f/128.f);
  float var = s2 * (1.f/128.f) - mean*mean;
  float inv = rsqrtf(var + 1e-5f);
  float2 ov;
  ov.x = (r0 - mean) * inv * g[j]   + bb[j];
  ov.y = (r1 - mean) * inv * g[j+1] + bb[j+1];
  *(float2*)&out[(size_t)t * Dd + j] = ov;

  if (blockIdx.x == 0 && tid == 0) {
    float m1s = 0.f;
    for (int e = 0; e < 8; ++e) m1s += imp[e];
    m1s *= 0.125f;
    float v1 = 0.f;
    for (int e = 0; e < 8; ++e) { float dd = imp[e] - m1s; v1 += dd * dd; }
    v1 *= 0.125f;
    float c1 = v1 / (m1s * m1s + 1e-10f);
    float m2 = 0.f;
    for (int e = 0; e < 8; ++e) m2 += loadv[e];
    m2 *= 0.125f;
    float v2 = 0.f;
    for (int e = 0; e < 8; ++e) { float dd = loadv[e] - m2; v2 += dd * dd; }
    v2 *= 0.125f;
    float c2 = v2 / (m2 * m2 + 1e-10f);
    out_loss[0] = (c1 + c2) * 0.01f;
  }
}

extern "C" void kernel_launch(void* const* d_in, const int* in_sizes, int n_in,
                              void* d_out, int out_size, void* d_ws, size_t ws_size,
                              hipStream_t stream)
{
  (void)in_sizes; (void)n_in; (void)out_size; (void)ws_size;
  const float* x      = (const float*)d_in[0];
  const float* Wq     = (const float*)d_in[1];
  const float* Wk     = (const float*)d_in[2];
  const float* Wv     = (const float*)d_in[3];
  const float* Wo     = (const float*)d_in[4];
  const float* bo     = (const float*)d_in[5];
  const float* ln1_g  = (const float*)d_in[6];
  const float* ln1_b  = (const float*)d_in[7];
  const float* w_gate = (const float*)d_in[8];
  const float* W1     = (const float*)d_in[9];
  const float* b1     = (const float*)d_in[10];
  const float* W2     = (const float*)d_in[11];
  const float* b2     = (const float*)d_in[12];
  const float* ln2_g  = (const float*)d_in[13];
  const float* ln2_b  = (const float*)d_in[14];

  char* wsb = (char*)d_ws;
  size_t off = 0;
  short* attn_b  = (short*)(wsb + off); off += (size_t)Tt*Dd*2;          //  3,276,800
  float* out1    = (float*)(wsb + off); off += (size_t)Tt*Dd*4;          //  6,553,600
  short* out1b   = (short*)(wsb + off); off += (size_t)Tt*Dd*2;          //  3,276,800
  short* moe0    = (short*)(wsb + off); off += (size_t)Tt*Dd*2;          //  3,276,800
  short* moe1    = (short*)(wsb + off); off += (size_t)Tt*Dd*2;          //  3,276,800
  short* q_bf    = (short*)(wsb + off); off += (size_t)256*400*16*2;     //  3,276,800
  short* k_bf    = (short*)(wsb + off); off += (size_t)256*400*16*2;     //  3,276,800
  short* v_bf    = (short*)(wsb + off); off += (size_t)256*400*16*2;     //  3,276,800
  short* W1t     = (short*)(wsb + off); off += (size_t)Ee*FFd*Dd*2;      //  1,048,576
  short* W2t     = (short*)(wsb + off); off += (size_t)Ee*FFd*Dd*2;      //  1,048,576
  short* wo_t    = (short*)(wsb + off); off += (size_t)Dd*Dd*2;          //     32,768
  short* qkvw    = (short*)(wsb + off); off += (size_t)384*Dd*2;         //     98,304
  int*   gmeta   = (int*)(wsb + off);   off += 256;
  int*   etok    = (int*)(wsb + off);   off += (size_t)Ee*Tt*4;          //    409,600
  float* egate   = (float*)(wsb + off); off += (size_t)Ee*Tt*4;          //    409,600

  int*   cnt   = gmeta;
  float* imp   = (float*)(gmeta + 8);
  float* loadv = (float*)(gmeta + 16);

  float* out3 = (float*)d_out;
  float* loss = out3 + Tt * Dd;

  prep_kernel<<<1088, 256, 0, stream>>>(W1, W2, Wo, Wq, Wk, Wv, W1t, W2t, wo_t, qkvw, gmeta);
  qkv_kernel<<<200, 256, 0, stream>>>(x, qkvw, q_bf, k_bf, v_bf);
  attn_kernel<<<256, 512, 0, stream>>>(q_bf, k_bf, v_bf, attn_b);
  proj_ln1_gate_kernel<<<200, 256, 0, stream>>>(x, attn_b, wo_t, bo, ln1_g, ln1_b, w_gate,
                                                out1, out1b, cnt, imp, loadv, etok, egate);
  moe_kernel<<<dim3(200, 8), 256, 0, stream>>>(out1b, W1t, b1, W2t, b2, cnt, etok, egate, moe0, moe1);
  ln2_kernel<<<3200, 256, 0, stream>>>(out1, moe0, moe1, ln2_g, ln2_b, imp, loadv, out3, loss);
}

// Round 13
// 96.217 us; speedup vs baseline: 1.2851x; 1.0561x over previous
//
#include <hip/hip_runtime.h>
#include <hip/hip_bf16.h>
#include <math.h>

#define Bb 32
#define Nn 400
#define Dd 128
#define Hh 8
#define QKd 16
#define FFd 512
#define Ee 8
#define Tt (Bb*Nn)   // 12800
#define KPAD 434     // VT row stride (bf16)
#define PP2 34       // P row stride (bf16 elems)

typedef __attribute__((ext_vector_type(8))) __bf16 bf16x8;
typedef __attribute__((ext_vector_type(4))) float f32x4;

#if defined(__has_builtin)
#if __has_builtin(__builtin_amdgcn_exp2f)
#define EXP2(x) __builtin_amdgcn_exp2f(x)
#endif
#endif
#ifndef EXP2
#define EXP2(x) __expf((x) * 0.69314718f)
#endif

// RNE f32->bf16 via HW cvt (compiler emits v_cvt_pk_bf16_f32 for pairs).
__device__ __forceinline__ unsigned short f2bfu(float f){
  union { __hip_bfloat16 h; unsigned short u; } v;
  v.h = __float2bfloat16(f);
  return v.u;
}
__device__ __forceinline__ short f2bf(float f){ return (short)f2bfu(f); }
__device__ __forceinline__ unsigned pack2bf(float a, float b){
  return (unsigned)f2bfu(a) | ((unsigned)f2bfu(b) << 16);
}
__device__ __forceinline__ bf16x8 zero_bf16x8(){
  union { uint4 u; bf16x8 b; } z;
  z.u.x = 0u; z.u.y = 0u; z.u.z = 0u; z.u.w = 0u;
  return z.b;
}

// ---------------- K0: prep — all weight transposes (f32 -> bf16^T) + zero gate meta ----------------
__global__ __launch_bounds__(256) void prep_kernel(
    const float* __restrict__ W1, const float* __restrict__ W2, const float* __restrict__ Wo,
    const float* __restrict__ Wq, const float* __restrict__ Wk, const float* __restrict__ Wv,
    short* __restrict__ W1t, short* __restrict__ W2t, short* __restrict__ wo_t,
    short* __restrict__ qkvw, int* __restrict__ gmeta)
{
  const int bid = blockIdx.x;
  if (bid == 0 && threadIdx.x < 24) gmeta[threadIdx.x] = 0;   // cnt[8], imp[8], loadv[8]

  const float* in; short* out; int C, tile;
  if (bid < 512)        { int e = bid >> 6;         tile = bid & 63;          in = W1 + e*65536; out = W1t + e*65536; C = 512; }
  else if (bid < 1024)  { int e = (bid - 512) >> 6; tile = (bid - 512) & 63;  in = W2 + e*65536; out = W2t + e*65536; C = 128; }
  else if (bid < 1040)  { tile = bid - 1024; in = Wo; out = wo_t;          C = 128; }
  else if (bid < 1056)  { tile = bid - 1040; in = Wq; out = qkvw;          C = 128; }
  else if (bid < 1072)  { tile = bid - 1056; in = Wk; out = qkvw + 16384;  C = 128; }
  else                  { tile = bid - 1072; in = Wv; out = qkvw + 32768;  C = 128; }
  const int R = (bid < 512) ? 128 : (bid < 1024 ? 512 : 128);

  __shared__ float t32[32][33];
  const int nCt = C >> 5;
  const int c0 = (tile % nCt) << 5;
  const int r0 = (tile / nCt) << 5;
  const int tx = threadIdx.x & 31, ty = threadIdx.x >> 5;
  #pragma unroll
  for (int i = 0; i < 4; ++i)
    t32[ty + 8*i][tx] = in[(size_t)(r0 + ty + 8*i) * C + c0 + tx];
  __syncthreads();
  #pragma unroll
  for (int i = 0; i < 4; ++i)
    out[(size_t)(c0 + ty + 8*i) * R + r0 + tx] = f2bf(t32[tx][ty + 8*i]);
}

// ---------------- K1: QKV projection via MFMA, split-bf16 activations ----------------
// grid 200, block 256. qkvw: [384][128] bf16. Outputs q,k,v all [BH][400][16] bf16 (q pre-scaled).
__global__ __launch_bounds__(256) void qkv_kernel(const float* __restrict__ x,
    const short* __restrict__ qkvw,
    short* __restrict__ q, short* __restrict__ k, short* __restrict__ v)
{
  __shared__ short xsh[64][136];
  __shared__ short xsl[64][136];
  const int tid = threadIdx.x;
  const int t0 = blockIdx.x * 64;

  #pragma unroll
  for (int it = 0; it < 8; ++it) {
    int lin = it * 256 + tid;
    int r = lin >> 5;
    int c4 = (lin & 31) << 2;
    float4 xv = *(const float4*)&x[(size_t)(t0 + r) * Dd + c4];
    unsigned h01 = pack2bf(xv.x, xv.y);
    unsigned h23 = pack2bf(xv.z, xv.w);
    union { unsigned u; float f; } ua, ub, uc, ud;
    ua.u = h01 << 16; ub.u = h01 & 0xFFFF0000u;
    uc.u = h23 << 16; ud.u = h23 & 0xFFFF0000u;
    unsigned l01 = pack2bf(xv.x - ua.f, xv.y - ub.f);
    unsigned l23 = pack2bf(xv.z - uc.f, xv.w - ud.f);
    uint2 ph; ph.x = h01; ph.y = h23;
    uint2 pl; pl.x = l01; pl.y = l23;
    *(uint2*)&xsh[r][c4] = ph;
    *(uint2*)&xsl[r][c4] = pl;
  }
  __syncthreads();

  const int lane = tid & 63, w = tid >> 6;
  const int l15 = lane & 15, l4 = lane >> 4;

  f32x4 zero4 = {0.f, 0.f, 0.f, 0.f};
  f32x4 acc[6][4];
  #pragma unroll
  for (int ot = 0; ot < 6; ++ot)
    #pragma unroll
    for (int mt = 0; mt < 4; ++mt) acc[ot][mt] = zero4;

  #pragma unroll
  for (int kt = 0; kt < 4; ++kt) {
    bf16x8 bmh[4], bml[4];
    #pragma unroll
    for (int mt = 0; mt < 4; ++mt) {
      bmh[mt] = *(const bf16x8*)&xsh[mt*16 + l15][kt*32 + l4*8];
      bml[mt] = *(const bf16x8*)&xsl[mt*16 + l15][kt*32 + l4*8];
    }
    #pragma unroll
    for (int ot = 0; ot < 6; ++ot) {
      bf16x8 a = *(const bf16x8*)&qkvw[(size_t)(w*96 + ot*16 + l15) * Dd + kt*32 + l4*8];
      #pragma unroll
      for (int mt = 0; mt < 4; ++mt) {
        acc[ot][mt] = __builtin_amdgcn_mfma_f32_16x16x32_bf16(a, bmh[mt], acc[ot][mt], 0, 0, 0);
        acc[ot][mt] = __builtin_amdgcn_mfma_f32_16x16x32_bf16(a, bml[mt], acc[ot][mt], 0, 0, 0);
      }
    }
  }

  #pragma unroll
  for (int ot = 0; ot < 6; ++ot) {
    const int ob = w*96 + ot*16;
    const int sel = ob >> 7;
    const int hz = (ob & 127) >> 4;
    #pragma unroll
    for (int mt = 0; mt < 4; ++mt) {
      int t = t0 + mt*16 + l15;
      int b = t / Nn, n = t - b * Nn;
      size_t bhn = (size_t)(b*Hh + hz) * Nn + n;
      f32x4 a = acc[ot][mt];
      uint2 p;
      if (sel == 0) {
        p.x = pack2bf(a[0]*0.36067376f, a[1]*0.36067376f);  // 0.25*log2(e)
        p.y = pack2bf(a[2]*0.36067376f, a[3]*0.36067376f);
        *(uint2*)&q[bhn*16 + l4*4] = p;
      } else if (sel == 1) {
        p.x = pack2bf(a[0], a[1]);
        p.y = pack2bf(a[2], a[3]);
        *(uint2*)&k[bhn*16 + l4*4] = p;
      } else {
        p.x = pack2bf(a[0], a[1]);
        p.y = pack2bf(a[2], a[3]);
        *(uint2*)&v[bhn*16 + l4*4] = p;
      }
    }
  }
}

// ---------------- K2: attention v3 — key-split, 16 waves/block ----------------
// grid 256 (bh), block 1024. Wave pair (p, p+8): p keeps R9's 4-q-tile loop over key
// chunks 0..6; p+8 over 7..12. Partial (o, lsum) summed via LDS (exact: unnormalized exp2).
__global__ __launch_bounds__(1024) void attn_kernel(const short* __restrict__ q,
    const short* __restrict__ k, const short* __restrict__ v, short* __restrict__ attn_b)
{
  __shared__ short VT[16 * KPAD];          // 13888 B
  __shared__ short P[16][4][16 * PP2];     // 69632 B (reused as combine buf)
  const int tid = threadIdx.x;
  const int bh = blockIdx.x;

  {
    const unsigned* vg = (const unsigned*)(v + (size_t)bh * 400 * 16);
    #pragma unroll
    for (int it = 0; it < 4; ++it) {
      int lin = it*1024 + tid;
      if (lin < 3200) {
        int key = lin >> 3, dp = lin & 7;
        unsigned pv = vg[key*8 + dp];
        VT[(2*dp)  * KPAD + key] = (short)(pv & 0xffffu);
        VT[(2*dp+1)* KPAD + key] = (short)(pv >> 16);
      }
    }
    if (tid < 256) {   // zero pad keys 400..415
      int d = tid >> 4, key = 400 + (tid & 15);
      VT[d*KPAD + key] = 0;
    }
  }
  __syncthreads();

  const int w = tid >> 6, lane = tid & 63;
  const int l15 = lane & 15, g = lane >> 4;
  const int p = w & 7, hh = w >> 3;
  const int cc0 = hh ? 7 : 0;
  const int cc1 = hh ? 13 : 7;

  f32x4 zero4 = {0.f, 0.f, 0.f, 0.f};
  f32x4 o[4];
  float lsum[4];
  bf16x8 qf[4];
  #pragma unroll
  for (int i = 0; i < 4; ++i) {
    o[i] = zero4; lsum[i] = 0.f;
    int qt = p + 8*i;
    if (qt < 25 && g < 2)
      qf[i] = *(const bf16x8*)&q[((size_t)bh*400 + qt*16 + l15)*16 + 8*g];
    else
      qf[i] = zero_bf16x8();
  }

  for (int cc = cc0; cc < cc1; ++cc) {
    #pragma unroll
    for (int sub = 0; sub < 2; ++sub) {
      const int kt = cc*2 + sub;
      if (kt < 25) {
        bf16x8 kf;
        if (g < 2) kf = *(const bf16x8*)&k[((size_t)bh*400 + kt*16 + l15)*16 + 8*g];
        else       kf = zero_bf16x8();
        #pragma unroll
        for (int i = 0; i < 4; ++i) {
          int qt = p + 8*i;
          if (qt < 25) {
            f32x4 s = __builtin_amdgcn_mfma_f32_16x16x32_bf16(kf, qf[i], zero4, 0, 0, 0);
            float p0 = EXP2(s[0]);
            float p1 = EXP2(s[1]);
            float p2 = EXP2(s[2]);
            float p3 = EXP2(s[3]);
            lsum[i] += (p0 + p1) + (p2 + p3);
            uint2 pk;
            pk.x = pack2bf(p0, p1);
            pk.y = pack2bf(p2, p3);
            *(uint2*)&P[w][i][l15*PP2 + sub*16 + 4*g] = pk;
          }
        }
      } else {   // kt == 25: keys 400..415 -> P = 0
        uint2 z; z.x = 0u; z.y = 0u;
        #pragma unroll
        for (int i = 0; i < 4; ++i) {
          int qt = p + 8*i;
          if (qt < 25) *(uint2*)&P[w][i][l15*PP2 + sub*16 + 4*g] = z;
        }
      }
    }
    bf16x8 vf = *(const bf16x8*)&VT[l15*KPAD + cc*32 + 8*g];
    #pragma unroll
    for (int i = 0; i < 4; ++i) {
      int qt = p + 8*i;
      if (qt < 25) {
        bf16x8 pf = *(const bf16x8*)&P[w][i][l15*PP2 + 8*g];
        o[i] = __builtin_amdgcn_mfma_f32_16x16x32_bf16(vf, pf, o[i], 0, 0, 0);
      }
    }
  }

  // reduce lsum over lane-groups within this wave (half-keys total)
  #pragma unroll
  for (int i = 0; i < 4; ++i) {
    lsum[i] += __shfl_xor(lsum[i], 16, 64);
    lsum[i] += __shfl_xor(lsum[i], 32, 64);
  }

  // combine halves via LDS (reuse P region; all P reads are complete after barrier)
  __syncthreads();
  float* CB = (float*)&P[0][0][0];   // 8 waves x 4 tiles x 64 lanes x 5 floats = 40960 B
  if (hh == 1) {
    #pragma unroll
    for (int i = 0; i < 4; ++i) {
      int qt = p + 8*i;
      if (qt < 25) {
        int base = (((p*4) + i)*64 + lane)*5;
        CB[base+0] = o[i][0]; CB[base+1] = o[i][1];
        CB[base+2] = o[i][2]; CB[base+3] = o[i][3];
        CB[base+4] = lsum[i];
      }
    }
  }
  __syncthreads();
  if (hh == 0) {
    const int b = bh >> 3, h = bh & 7;
    #pragma unroll
    for (int i = 0; i < 4; ++i) {
      int qt = p + 8*i;
      if (qt < 25) {
        int base = (((p*4) + i)*64 + lane)*5;
        float o0 = o[i][0] + CB[base+0];
        float o1 = o[i][1] + CB[base+1];
        float o2 = o[i][2] + CB[base+2];
        float o3 = o[i][3] + CB[base+3];
        float ls = lsum[i] + CB[base+4];
        float inv = 1.f / ls;
        uint2 pk;
        pk.x = pack2bf(o0*inv, o1*inv);
        pk.y = pack2bf(o2*inv, o3*inv);
        *(uint2*)&attn_b[((size_t)b*Nn + qt*16 + l15)*Dd + h*16 + 4*g] = pk;
      }
    }
  }
}

// ---------------- K3: output proj (MFMA) + residual + LN1 + gating, fused ----------------
// grid 200, block 256 (4 waves x 32 outdims; 64 tokens/block). Writes bf16 out1b only.
__global__ __launch_bounds__(256) void proj_ln1_gate_kernel(
    const float* __restrict__ x, const short* __restrict__ attn_b,
    const short* __restrict__ wo_t, const float* __restrict__ bo,
    const float* __restrict__ g1, const float* __restrict__ b1n,
    const float* __restrict__ w_gate,
    short* __restrict__ out1b,
    int* __restrict__ cnt, float* __restrict__ imp, float* __restrict__ loadv,
    int* __restrict__ etok, float* __restrict__ egate)
{
  __shared__ short as_[64][136];
  __shared__ float reds[4][64];
  __shared__ float reds2[4][64];
  __shared__ float mv[64][2];
  __shared__ float lgs[64*8];
  __shared__ float wgs[128*8];
  __shared__ float s_imp[8], s_load[8];
  __shared__ int s_cnt[8], s_base[8];

  const int tid = threadIdx.x;
  const int t0 = blockIdx.x * 64;

  #pragma unroll
  for (int it = 0; it < 8; ++it) {
    int lin = it * 256 + tid;
    int r = lin >> 5;
    int c4 = (lin & 31) << 2;
    *(uint2*)&as_[r][c4] = *(const uint2*)&attn_b[(size_t)(t0 + r) * Dd + c4];
  }
  #pragma unroll
  for (int it = 0; it < 4; ++it) wgs[it*256 + tid] = w_gate[it*256 + tid];
  lgs[tid] = 0.f; lgs[tid + 256] = 0.f;
  if (tid < 8) { s_imp[tid] = 0.f; s_load[tid] = 0.f; s_cnt[tid] = 0; }
  __syncthreads();

  const int lane = tid & 63, w = tid >> 6;
  const int l15 = lane & 15, l4 = lane >> 4;

  f32x4 zero4 = {0.f, 0.f, 0.f, 0.f};
  f32x4 y[2][4];
  #pragma unroll
  for (int dt = 0; dt < 2; ++dt)
    #pragma unroll
    for (int mt = 0; mt < 4; ++mt) y[dt][mt] = zero4;

  #pragma unroll
  for (int kt = 0; kt < 4; ++kt) {
    bf16x8 a0 = *(const bf16x8*)&wo_t[(size_t)(w*32 + l15) * Dd + kt*32 + l4*8];
    bf16x8 a1 = *(const bf16x8*)&wo_t[(size_t)(w*32 + 16 + l15) * Dd + kt*32 + l4*8];
    bf16x8 bm[4];
    #pragma unroll
    for (int mt = 0; mt < 4; ++mt)
      bm[mt] = *(const bf16x8*)&as_[mt*16 + l15][kt*32 + l4*8];
    #pragma unroll
    for (int mt = 0; mt < 4; ++mt) {
      y[0][mt] = __builtin_amdgcn_mfma_f32_16x16x32_bf16(a0, bm[mt], y[0][mt], 0, 0, 0);
      y[1][mt] = __builtin_amdgcn_mfma_f32_16x16x32_bf16(a1, bm[mt], y[1][mt], 0, 0, 0);
    }
  }

  float4 bov[2];
  bov[0] = *(const float4*)&bo[w*32 + 0*16 + l4*4];
  bov[1] = *(const float4*)&bo[w*32 + 1*16 + l4*4];
  float sP[4], s2P[4];
  #pragma unroll
  for (int mt = 0; mt < 4; ++mt) { sP[mt] = 0.f; s2P[mt] = 0.f; }
  #pragma unroll
  for (int mt = 0; mt < 4; ++mt) {
    int row = mt*16 + l15;
    #pragma unroll
    for (int dt = 0; dt < 2; ++dt) {
      int dim = w*32 + dt*16 + l4*4;
      float4 xv = *(const float4*)&x[(size_t)(t0 + row) * Dd + dim];
      float4 bv = bov[dt];
      f32x4 r = y[dt][mt];
      r[0] += bv.x + xv.x; r[1] += bv.y + xv.y;
      r[2] += bv.z + xv.z; r[3] += bv.w + xv.w;
      y[dt][mt] = r;
      sP[mt]  += (r[0] + r[1]) + (r[2] + r[3]);
      s2P[mt] += (r[0]*r[0] + r[1]*r[1]) + (r[2]*r[2] + r[3]*r[3]);
    }
  }
  #pragma unroll
  for (int mt = 0; mt < 4; ++mt) {
    sP[mt]  += __shfl_xor(sP[mt], 16, 64);  sP[mt]  += __shfl_xor(sP[mt], 32, 64);
    s2P[mt] += __shfl_xor(s2P[mt], 16, 64); s2P[mt] += __shfl_xor(s2P[mt], 32, 64);
  }
  if (l4 == 0) {
    #pragma unroll
    for (int mt = 0; mt < 4; ++mt) {
      reds[w][mt*16 + l15] = sP[mt];
      reds2[w][mt*16 + l15] = s2P[mt];
    }
  }
  __syncthreads();
  if (tid < 64) {
    float s = reds[0][tid] + reds[1][tid] + reds[2][tid] + reds[3][tid];
    float s2 = reds2[0][tid] + reds2[1][tid] + reds2[2][tid] + reds2[3][tid];
    float m = s * (1.f/128.f);
    float var = s2 * (1.f/128.f) - m*m;
    mv[tid][0] = m;
    mv[tid][1] = rsqrtf(var + 1e-5f);
  }
  __syncthreads();

  float4 gv[2], bv2[2];
  #pragma unroll
  for (int dt = 0; dt < 2; ++dt) {
    gv[dt]  = *(const float4*)&g1[w*32 + dt*16 + l4*4];
    bv2[dt] = *(const float4*)&b1n[w*32 + dt*16 + l4*4];
  }
  #pragma unroll
  for (int mt = 0; mt < 4; ++mt) {
    int row = mt*16 + l15;
    float m = mv[row][0], inv = mv[row][1];
    float lg[8];
    #pragma unroll
    for (int e = 0; e < 8; ++e) lg[e] = 0.f;
    #pragma unroll
    for (int dt = 0; dt < 2; ++dt) {
      int dim = w*32 + dt*16 + l4*4;
      f32x4 r = y[dt][mt];
      float o0 = (r[0]-m)*inv*((float*)&gv[dt])[0] + ((float*)&bv2[dt])[0];
      float o1 = (r[1]-m)*inv*((float*)&gv[dt])[1] + ((float*)&bv2[dt])[1];
      float o2 = (r[2]-m)*inv*((float*)&gv[dt])[2] + ((float*)&bv2[dt])[2];
      float o3 = (r[3]-m)*inv*((float*)&gv[dt])[3] + ((float*)&bv2[dt])[3];
      uint2 p; p.x = pack2bf(o0, o1); p.y = pack2bf(o2, o3);
      *(uint2*)&out1b[(size_t)(t0 + row) * Dd + dim] = p;
      #pragma unroll
      for (int e = 0; e < 8; ++e)
        lg[e] += o0*wgs[(dim+0)*8+e] + o1*wgs[(dim+1)*8+e]
               + o2*wgs[(dim+2)*8+e] + o3*wgs[(dim+3)*8+e];
    }
    #pragma unroll
    for (int e = 0; e < 8; ++e) {
      lg[e] += __shfl_xor(lg[e], 16, 64);
      lg[e] += __shfl_xor(lg[e], 32, 64);
    }
    if (l4 == 0) {
      #pragma unroll
      for (int e = 0; e < 8; ++e) atomicAdd(&lgs[row*8 + e], lg[e]);
    }
  }
  __syncthreads();

  int i0 = 0, i1 = -1, p0 = 0, p1 = 0;
  float g0 = 0.f, gg1 = 0.f;
  if (tid < 64) {
    float lgv[8];
    #pragma unroll
    for (int e = 0; e < 8; ++e) lgv[e] = lgs[tid*8 + e];
    float v0 = lgv[0];
    #pragma unroll
    for (int e = 1; e < 8; ++e) if (lgv[e] > v0) { v0 = lgv[e]; i0 = e; }
    float v1 = -INFINITY;
    #pragma unroll
    for (int e = 0; e < 8; ++e) if (e != i0 && lgv[e] > v1) { v1 = lgv[e]; i1 = e; }
    g0 = 1.f / (1.f + __expf(v1 - v0));
    gg1 = 1.f - g0;
    atomicAdd(&s_imp[i0], g0);  atomicAdd(&s_imp[i1], gg1);
    atomicAdd(&s_load[i0], 1.f); atomicAdd(&s_load[i1], 1.f);
    p0 = atomicAdd(&s_cnt[i0], 1);
    p1 = atomicAdd(&s_cnt[i1], 1);
  }
  __syncthreads();
  if (tid < 8) {
    s_base[tid] = atomicAdd(&cnt[tid], s_cnt[tid]);
    atomicAdd(&imp[tid], s_imp[tid]);
    atomicAdd(&loadv[tid], s_load[tid]);
  }
  __syncthreads();
  if (tid < 64) {
    int t = t0 + tid;
    int o0 = i0 * Tt + s_base[i0] + p0;
    etok[o0] = t;               egate[o0] = g0;
    int o1 = i1 * Tt + s_base[i1] + p1;
    etok[o1] = t | (1 << 30);   egate[o1] = gg1;
  }
}

// ---------------- K6: grouped sparse MoE FFN (MFMA bf16, bf16 in/out) ----------------
__global__ __launch_bounds__(256) void moe_kernel(const short* __restrict__ out1b,
    const short* __restrict__ W1t, const float* __restrict__ b1,
    const short* __restrict__ W2t, const float* __restrict__ b2,
    const int* __restrict__ cnt, const int* __restrict__ etok, const float* __restrict__ egate,
    short* __restrict__ moe0, short* __restrict__ moe1)
{
  __shared__ short xs[64][136];
  __shared__ short hs[64][136];
  __shared__ int els[64];
  __shared__ float gls[64];

  const int e = blockIdx.y;
  const int count = cnt[e];
  const int t0 = blockIdx.x * 64;
  if (t0 >= count) return;
  const int nt = min(64, count - t0);
  const int tid = threadIdx.x;

  if (tid < 64) {
    int idx = (tid < nt) ? tid : 0;
    els[tid] = etok[e * Tt + t0 + idx];
    gls[tid] = (tid < nt) ? egate[e * Tt + t0 + tid] : 0.f;
  }
  __syncthreads();

  #pragma unroll
  for (int it = 0; it < 8; ++it) {
    int lin = it * 256 + tid;
    int r = lin >> 5;
    int c4 = (lin & 31) << 2;
    int tok = els[r] & 0x3FFFFFFF;
    *(uint2*)&xs[r][c4] = *(const uint2*)&out1b[(size_t)tok * Dd + c4];
  }
  __syncthreads();

  const int lane = tid & 63;
  const int w = tid >> 6;
  const int l15 = lane & 15;
  const int l4 = lane >> 4;

  f32x4 zero4 = {0.f, 0.f, 0.f, 0.f};
  f32x4 y[2][4];
  #pragma unroll
  for (int dt = 0; dt < 2; ++dt)
    #pragma unroll
    for (int mt = 0; mt < 4; ++mt) y[dt][mt] = zero4;

  const short* W1p = W1t + (size_t)e * FFd * Dd;
  const short* W2p = W2t + (size_t)e * Dd * FFd;

  for (int ch = 0; ch < 4; ++ch) {
    f32x4 h[2][4];
    #pragma unroll
    for (int ft = 0; ft < 2; ++ft)
      #pragma unroll
      for (int mt = 0; mt < 4; ++mt) h[ft][mt] = zero4;

    #pragma unroll
    for (int kt = 0; kt < 4; ++kt) {
      bf16x8 a0 = *(const bf16x8*)&W1p[(size_t)(ch*128 + w*32 + 0*16 + l15) * Dd + kt*32 + l4*8];
      bf16x8 a1 = *(const bf16x8*)&W1p[(size_t)(ch*128 + w*32 + 1*16 + l15) * Dd + kt*32 + l4*8];
      bf16x8 bm[4];
      #pragma unroll
      for (int mt = 0; mt < 4; ++mt)
        bm[mt] = *(const bf16x8*)&xs[mt*16 + l15][kt*32 + l4*8];
      #pragma unroll
      for (int mt = 0; mt < 4; ++mt) {
        h[0][mt] = __builtin_amdgcn_mfma_f32_16x16x32_bf16(a0, bm[mt], h[0][mt], 0, 0, 0);
        h[1][mt] = __builtin_amdgcn_mfma_f32_16x16x32_bf16(a1, bm[mt], h[1][mt], 0, 0, 0);
      }
    }

    float4 b1v0 = *(const float4*)&b1[e*FFd + ch*128 + w*32 + 0*16 + l4*4];
    float4 b1v1 = *(const float4*)&b1[e*FFd + ch*128 + w*32 + 1*16 + l4*4];
    __syncthreads();
    #pragma unroll
    for (int mt = 0; mt < 4; ++mt) {
      uint2 p0, p1;
      p0.x = pack2bf(fmaxf(h[0][mt][0] + b1v0.x, 0.f), fmaxf(h[0][mt][1] + b1v0.y, 0.f));
      p0.y = pack2bf(fmaxf(h[0][mt][2] + b1v0.z, 0.f), fmaxf(h[0][mt][3] + b1v0.w, 0.f));
      *(uint2*)&hs[mt*16 + l15][w*32 + 0*16 + l4*4] = p0;
      p1.x = pack2bf(fmaxf(h[1][mt][0] + b1v1.x, 0.f), fmaxf(h[1][mt][1] + b1v1.y, 0.f));
      p1.y = pack2bf(fmaxf(h[1][mt][2] + b1v1.z, 0.f), fmaxf(h[1][mt][3] + b1v1.w, 0.f));
      *(uint2*)&hs[mt*16 + l15][w*32 + 1*16 + l4*4] = p1;
    }
    __syncthreads();

    #pragma unroll
    for (int kt = 0; kt < 4; ++kt) {
      bf16x8 a0 = *(const bf16x8*)&W2p[(size_t)(w*32 + 0*16 + l15) * FFd + ch*128 + kt*32 + l4*8];
      bf16x8 a1 = *(const bf16x8*)&W2p[(size_t)(w*32 + 1*16 + l15) * FFd + ch*128 + kt*32 + l4*8];
      bf16x8 bm[4];
      #pragma unroll
      for (int mt = 0; mt < 4; ++mt)
        bm[mt] = *(const bf16x8*)&hs[mt*16 + l15][kt*32 + l4*8];
      #pragma unroll
      for (int mt = 0; mt < 4; ++mt) {
        y[0][mt] = __builtin_amdgcn_mfma_f32_16x16x32_bf16(a0, bm[mt], y[0][mt], 0, 0, 0);
        y[1][mt] = __builtin_amdgcn_mfma_f32_16x16x32_bf16(a1, bm[mt], y[1][mt], 0, 0, 0);
      }
    }
  }

  float4 b2v[2];
  b2v[0] = *(const float4*)&b2[e*Dd + w*32 + 0*16 + l4*4];
  b2v[1] = *(const float4*)&b2[e*Dd + w*32 + 1*16 + l4*4];
  #pragma unroll
  for (int mt = 0; mt < 4; ++mt) {
    int m = mt*16 + l15;
    if (m < nt) {
      int raw = els[m];
      int t = raw & 0x3FFFFFFF;
      float g = gls[m];
      short* basep = (raw & (1 << 30)) ? moe1 : moe0;
      #pragma unroll
      for (int dt = 0; dt < 2; ++dt) {
        float v0 = g * (y[dt][mt][0] + ((dt == 0) ? b2v[0].x : b2v[1].x));
        float v1 = g * (y[dt][mt][1] + ((dt == 0) ? b2v[0].y : b2v[1].y));
        float v2 = g * (y[dt][mt][2] + ((dt == 0) ? b2v[0].z : b2v[1].z));
        float v3 = g * (y[dt][mt][3] + ((dt == 0) ? b2v[0].w : b2v[1].w));
        uint2 p; p.x = pack2bf(v0, v1); p.y = pack2bf(v2, v3);
        *(uint2*)&basep[(size_t)t * Dd + w*32 + dt*16 + l4*4] = p;
      }
    }
  }
}

// ---------------- K7: residual (bf16) + LN2 -> d_out (+ loss in block 0) ----------------
// grid 3200, block 256 (one wave per token; no LDS).
__global__ __launch_bounds__(256) void ln2_kernel(const short* __restrict__ out1b,
    const short* __restrict__ moe0, const short* __restrict__ moe1,
    const float* __restrict__ g, const float* __restrict__ bb,
    const float* __restrict__ imp, const float* __restrict__ loadv,
    float* __restrict__ out, float* __restrict__ out_loss)
{
  const int tid = threadIdx.x;
  const int lane = tid & 63;
  const int t = blockIdx.x * 4 + (tid >> 6);
  const int j = lane * 2;

  unsigned xo = *(const unsigned*)&out1b[(size_t)t * Dd + j];
  unsigned m0 = *(const unsigned*)&moe0[(size_t)t * Dd + j];
  unsigned m1 = *(const unsigned*)&moe1[(size_t)t * Dd + j];
  union { unsigned u; float f; } xa, xb, a, b, c, d;
  xa.u = xo << 16; xb.u = xo & 0xFFFF0000u;
  a.u = m0 << 16; b.u = m0 & 0xFFFF0000u;
  c.u = m1 << 16; d.u = m1 & 0xFFFF0000u;
  float r0 = xa.f + a.f + c.f;
  float r1 = xb.f + b.f + d.f;

  float s = r0 + r1;
  float s2 = r0*r0 + r1*r1;
  #pragma unroll
  for (int off = 32; off > 0; off >>= 1) {
    s  += __shfl_xor(s, off, 64);
    s2 += __shfl_xor(s2, off, 64);
  }
  float mean = s * (1.f/128.f);
  float var = s2 * (1.f/128.f) - mean*mean;
  float inv = rsqrtf(var + 1e-5f);
  float2 ov;
  ov.x = (r0 - mean) * inv * g[j]   + bb[j];
  ov.y = (r1 - mean) * inv * g[j+1] + bb[j+1];
  *(float2*)&out[(size_t)t * Dd + j] = ov;

  if (blockIdx.x == 0 && tid == 0) {
    float m1s = 0.f;
    for (int e = 0; e < 8; ++e) m1s += imp[e];
    m1s *= 0.125f;
    float v1 = 0.f;
    for (int e = 0; e < 8; ++e) { float dd = imp[e] - m1s; v1 += dd * dd; }
    v1 *= 0.125f;
    float c1 = v1 / (m1s * m1s + 1e-10f);
    float m2 = 0.f;
    for (int e = 0; e < 8; ++e) m2 += loadv[e];
    m2 *= 0.125f;
    float v2 = 0.f;
    for (int e = 0; e < 8; ++e) { float dd = loadv[e] - m2; v2 += dd * dd; }
    v2 *= 0.125f;
    float c2 = v2 / (m2 * m2 + 1e-10f);
    out_loss[0] = (c1 + c2) * 0.01f;
  }
}

extern "C" void kernel_launch(void* const* d_in, const int* in_sizes, int n_in,
                              void* d_out, int out_size, void* d_ws, size_t ws_size,
                              hipStream_t stream)
{
  (void)in_sizes; (void)n_in; (void)out_size; (void)ws_size;
  const float* x      = (const float*)d_in[0];
  const float* Wq     = (const float*)d_in[1];
  const float* Wk     = (const float*)d_in[2];
  const float* Wv     = (const float*)d_in[3];
  const float* Wo     = (const float*)d_in[4];
  const float* bo     = (const float*)d_in[5];
  const float* ln1_g  = (const float*)d_in[6];
  const float* ln1_b  = (const float*)d_in[7];
  const float* w_gate = (const float*)d_in[8];
  const float* W1     = (const float*)d_in[9];
  const float* b1     = (const float*)d_in[10];
  const float* W2     = (const float*)d_in[11];
  const float* b2     = (const float*)d_in[12];
  const float* ln2_g  = (const float*)d_in[13];
  const float* ln2_b  = (const float*)d_in[14];

  char* wsb = (char*)d_ws;
  size_t off = 0;
  short* attn_b  = (short*)(wsb + off); off += (size_t)Tt*Dd*2;          //  3,276,800
  short* out1b   = (short*)(wsb + off); off += (size_t)Tt*Dd*2;          //  3,276,800
  short* moe0    = (short*)(wsb + off); off += (size_t)Tt*Dd*2;          //  3,276,800
  short* moe1    = (short*)(wsb + off); off += (size_t)Tt*Dd*2;          //  3,276,800
  short* q_bf    = (short*)(wsb + off); off += (size_t)256*400*16*2;     //  3,276,800
  short* k_bf    = (short*)(wsb + off); off += (size_t)256*400*16*2;     //  3,276,800
  short* v_bf    = (short*)(wsb + off); off += (size_t)256*400*16*2;     //  3,276,800
  short* W1t     = (short*)(wsb + off); off += (size_t)Ee*FFd*Dd*2;      //  1,048,576
  short* W2t     = (short*)(wsb + off); off += (size_t)Ee*FFd*Dd*2;      //  1,048,576
  short* wo_t    = (short*)(wsb + off); off += (size_t)Dd*Dd*2;          //     32,768
  short* qkvw    = (short*)(wsb + off); off += (size_t)384*Dd*2;         //     98,304
  int*   gmeta   = (int*)(wsb + off);   off += 256;
  int*   etok    = (int*)(wsb + off);   off += (size_t)Ee*Tt*4;          //    409,600
  float* egate   = (float*)(wsb + off); off += (size_t)Ee*Tt*4;          //    409,600

  int*   cnt   = gmeta;
  float* imp   = (float*)(gmeta + 8);
  float* loadv = (float*)(gmeta + 16);

  float* out3 = (float*)d_out;
  float* loss = out3 + Tt * Dd;

  prep_kernel<<<1088, 256, 0, stream>>>(W1, W2, Wo, Wq, Wk, Wv, W1t, W2t, wo_t, qkvw, gmeta);
  qkv_kernel<<<200, 256, 0, stream>>>(x, qkvw, q_bf, k_bf, v_bf);
  attn_kernel<<<256, 1024, 0, stream>>>(q_bf, k_bf, v_bf, attn_b);
  proj_ln1_gate_kernel<<<200, 256, 0, stream>>>(x, attn_b, wo_t, bo, ln1_g, ln1_b, w_gate,
                                                out1b, cnt, imp, loadv, etok, egate);
  moe_kernel<<<dim3(200, 8), 256, 0, stream>>>(out1b, W1t, b1, W2t, b2, cnt, etok, egate, moe0, moe1);
  ln2_kernel<<<3200, 256, 0, stream>>>(out1b, moe0, moe1, ln2_g, ln2_b, imp, loadv, out3, loss);
}

// Round 14
// 78.177 us; speedup vs baseline: 1.5816x; 1.2308x over previous
//
#include <hip/hip_runtime.h>
#include <hip/hip_bf16.h>
#include <math.h>

#define Bb 32
#define Nn 400
#define Dd 128
#define Hh 8
#define QKd 16
#define FFd 512
#define Ee 8
#define Tt (Bb*Nn)   // 12800
#define KPAD 434     // VT row stride (bf16)
#define PP2 34       // P row stride (bf16 elems)

typedef __attribute__((ext_vector_type(8))) __bf16 bf16x8;
typedef __attribute__((ext_vector_type(4))) float f32x4;

#if defined(__has_builtin)
#if __has_builtin(__builtin_amdgcn_exp2f)
#define EXP2(x) __builtin_amdgcn_exp2f(x)
#endif
#endif
#ifndef EXP2
#define EXP2(x) __expf((x) * 0.69314718f)
#endif

// RNE f32->bf16 via HW cvt (compiler emits v_cvt_pk_bf16_f32 for pairs).
__device__ __forceinline__ unsigned short f2bfu(float f){
  union { __hip_bfloat16 h; unsigned short u; } v;
  v.h = __float2bfloat16(f);
  return v.u;
}
__device__ __forceinline__ short f2bf(float f){ return (short)f2bfu(f); }
__device__ __forceinline__ unsigned pack2bf(float a, float b){
  return (unsigned)f2bfu(a) | ((unsigned)f2bfu(b) << 16);
}
__device__ __forceinline__ bf16x8 zero_bf16x8(){
  union { uint4 u; bf16x8 b; } z;
  z.u.x = 0u; z.u.y = 0u; z.u.z = 0u; z.u.w = 0u;
  return z.b;
}

// ---------------- K0: prep — all weight transposes (f32 -> bf16^T) + zero gate meta ----------------
__global__ __launch_bounds__(256) void prep_kernel(
    const float* __restrict__ W1, const float* __restrict__ W2, const float* __restrict__ Wo,
    const float* __restrict__ Wq, const float* __restrict__ Wk, const float* __restrict__ Wv,
    short* __restrict__ W1t, short* __restrict__ W2t, short* __restrict__ wo_t,
    short* __restrict__ qkvw, int* __restrict__ gmeta)
{
  const int bid = blockIdx.x;
  if (bid == 0 && threadIdx.x < 24) gmeta[threadIdx.x] = 0;   // cnt[8], imp[8], loadv[8]

  const float* in; short* out; int C, tile;
  if (bid < 512)        { int e = bid >> 6;         tile = bid & 63;          in = W1 + e*65536; out = W1t + e*65536; C = 512; }
  else if (bid < 1024)  { int e = (bid - 512) >> 6; tile = (bid - 512) & 63;  in = W2 + e*65536; out = W2t + e*65536; C = 128; }
  else if (bid < 1040)  { tile = bid - 1024; in = Wo; out = wo_t;          C = 128; }
  else if (bid < 1056)  { tile = bid - 1040; in = Wq; out = qkvw;          C = 128; }
  else if (bid < 1072)  { tile = bid - 1056; in = Wk; out = qkvw + 16384;  C = 128; }
  else                  { tile = bid - 1072; in = Wv; out = qkvw + 32768;  C = 128; }
  const int R = (bid < 512) ? 128 : (bid < 1024 ? 512 : 128);

  __shared__ float t32[32][33];
  const int nCt = C >> 5;
  const int c0 = (tile % nCt) << 5;
  const int r0 = (tile / nCt) << 5;
  const int tx = threadIdx.x & 31, ty = threadIdx.x >> 5;
  #pragma unroll
  for (int i = 0; i < 4; ++i)
    t32[ty + 8*i][tx] = in[(size_t)(r0 + ty + 8*i) * C + c0 + tx];
  __syncthreads();
  #pragma unroll
  for (int i = 0; i < 4; ++i)
    out[(size_t)(c0 + ty + 8*i) * R + r0 + tx] = f2bf(t32[tx][ty + 8*i]);
}

// ---------------- K1: QKV projection via MFMA, split-bf16, 8 waves ----------------
// grid 200, block 512 (8 waves x 48 outdims; 64 tokens/block).
__global__ __launch_bounds__(512) void qkv_kernel(const float* __restrict__ x,
    const short* __restrict__ qkvw,
    short* __restrict__ q, short* __restrict__ k, short* __restrict__ v)
{
  __shared__ short xsh[64][136];
  __shared__ short xsl[64][136];
  const int tid = threadIdx.x;
  const int t0 = blockIdx.x * 64;

  #pragma unroll
  for (int it = 0; it < 4; ++it) {
    int lin = it * 512 + tid;
    int r = lin >> 5;
    int c4 = (lin & 31) << 2;
    float4 xv = *(const float4*)&x[(size_t)(t0 + r) * Dd + c4];
    unsigned h01 = pack2bf(xv.x, xv.y);
    unsigned h23 = pack2bf(xv.z, xv.w);
    union { unsigned u; float f; } ua, ub, uc, ud;
    ua.u = h01 << 16; ub.u = h01 & 0xFFFF0000u;
    uc.u = h23 << 16; ud.u = h23 & 0xFFFF0000u;
    unsigned l01 = pack2bf(xv.x - ua.f, xv.y - ub.f);
    unsigned l23 = pack2bf(xv.z - uc.f, xv.w - ud.f);
    uint2 ph; ph.x = h01; ph.y = h23;
    uint2 pl; pl.x = l01; pl.y = l23;
    *(uint2*)&xsh[r][c4] = ph;
    *(uint2*)&xsl[r][c4] = pl;
  }
  __syncthreads();

  const int lane = tid & 63, w = tid >> 6;
  const int l15 = lane & 15, l4 = lane >> 4;

  f32x4 zero4 = {0.f, 0.f, 0.f, 0.f};
  f32x4 acc[3][4];
  #pragma unroll
  for (int ot = 0; ot < 3; ++ot)
    #pragma unroll
    for (int mt = 0; mt < 4; ++mt) acc[ot][mt] = zero4;

  #pragma unroll
  for (int kt = 0; kt < 4; ++kt) {
    bf16x8 bmh[4], bml[4];
    #pragma unroll
    for (int mt = 0; mt < 4; ++mt) {
      bmh[mt] = *(const bf16x8*)&xsh[mt*16 + l15][kt*32 + l4*8];
      bml[mt] = *(const bf16x8*)&xsl[mt*16 + l15][kt*32 + l4*8];
    }
    #pragma unroll
    for (int ot = 0; ot < 3; ++ot) {
      bf16x8 a = *(const bf16x8*)&qkvw[(size_t)(w*48 + ot*16 + l15) * Dd + kt*32 + l4*8];
      #pragma unroll
      for (int mt = 0; mt < 4; ++mt) {
        acc[ot][mt] = __builtin_amdgcn_mfma_f32_16x16x32_bf16(a, bmh[mt], acc[ot][mt], 0, 0, 0);
        acc[ot][mt] = __builtin_amdgcn_mfma_f32_16x16x32_bf16(a, bml[mt], acc[ot][mt], 0, 0, 0);
      }
    }
  }

  #pragma unroll
  for (int ot = 0; ot < 3; ++ot) {
    const int ob = w*48 + ot*16;
    const int sel = ob >> 7;
    const int hz = (ob & 127) >> 4;
    #pragma unroll
    for (int mt = 0; mt < 4; ++mt) {
      int t = t0 + mt*16 + l15;
      int b = t / Nn, n = t - b * Nn;
      size_t bhn = (size_t)(b*Hh + hz) * Nn + n;
      f32x4 a = acc[ot][mt];
      uint2 p;
      if (sel == 0) {
        p.x = pack2bf(a[0]*0.36067376f, a[1]*0.36067376f);  // 0.25*log2(e)
        p.y = pack2bf(a[2]*0.36067376f, a[3]*0.36067376f);
        *(uint2*)&q[bhn*16 + l4*4] = p;
      } else if (sel == 1) {
        p.x = pack2bf(a[0], a[1]);
        p.y = pack2bf(a[2], a[3]);
        *(uint2*)&k[bhn*16 + l4*4] = p;
      } else {
        p.x = pack2bf(a[0], a[1]);
        p.y = pack2bf(a[2], a[3]);
        *(uint2*)&v[bhn*16 + l4*4] = p;
      }
    }
  }
}

// ---------------- K2: attention v3 — key-split, 16 waves/block (R13, proven) ----------------
__global__ __launch_bounds__(1024) void attn_kernel(const short* __restrict__ q,
    const short* __restrict__ k, const short* __restrict__ v, short* __restrict__ attn_b)
{
  __shared__ short VT[16 * KPAD];          // 13888 B
  __shared__ short P[16][4][16 * PP2];     // 69632 B (reused as combine buf)
  const int tid = threadIdx.x;
  const int bh = blockIdx.x;

  {
    const unsigned* vg = (const unsigned*)(v + (size_t)bh * 400 * 16);
    #pragma unroll
    for (int it = 0; it < 4; ++it) {
      int lin = it*1024 + tid;
      if (lin < 3200) {
        int key = lin >> 3, dp = lin & 7;
        unsigned pv = vg[key*8 + dp];
        VT[(2*dp)  * KPAD + key] = (short)(pv & 0xffffu);
        VT[(2*dp+1)* KPAD + key] = (short)(pv >> 16);
      }
    }
    if (tid < 256) {
      int d = tid >> 4, key = 400 + (tid & 15);
      VT[d*KPAD + key] = 0;
    }
  }
  __syncthreads();

  const int w = tid >> 6, lane = tid & 63;
  const int l15 = lane & 15, g = lane >> 4;
  const int p = w & 7, hh = w >> 3;
  const int cc0 = hh ? 7 : 0;
  const int cc1 = hh ? 13 : 7;

  f32x4 zero4 = {0.f, 0.f, 0.f, 0.f};
  f32x4 o[4];
  float lsum[4];
  bf16x8 qf[4];
  #pragma unroll
  for (int i = 0; i < 4; ++i) {
    o[i] = zero4; lsum[i] = 0.f;
    int qt = p + 8*i;
    if (qt < 25 && g < 2)
      qf[i] = *(const bf16x8*)&q[((size_t)bh*400 + qt*16 + l15)*16 + 8*g];
    else
      qf[i] = zero_bf16x8();
  }

  for (int cc = cc0; cc < cc1; ++cc) {
    #pragma unroll
    for (int sub = 0; sub < 2; ++sub) {
      const int kt = cc*2 + sub;
      if (kt < 25) {
        bf16x8 kf;
        if (g < 2) kf = *(const bf16x8*)&k[((size_t)bh*400 + kt*16 + l15)*16 + 8*g];
        else       kf = zero_bf16x8();
        #pragma unroll
        for (int i = 0; i < 4; ++i) {
          int qt = p + 8*i;
          if (qt < 25) {
            f32x4 s = __builtin_amdgcn_mfma_f32_16x16x32_bf16(kf, qf[i], zero4, 0, 0, 0);
            float p0 = EXP2(s[0]);
            float p1 = EXP2(s[1]);
            float p2 = EXP2(s[2]);
            float p3 = EXP2(s[3]);
            lsum[i] += (p0 + p1) + (p2 + p3);
            uint2 pk;
            pk.x = pack2bf(p0, p1);
            pk.y = pack2bf(p2, p3);
            *(uint2*)&P[w][i][l15*PP2 + sub*16 + 4*g] = pk;
          }
        }
      } else {
        uint2 z; z.x = 0u; z.y = 0u;
        #pragma unroll
        for (int i = 0; i < 4; ++i) {
          int qt = p + 8*i;
          if (qt < 25) *(uint2*)&P[w][i][l15*PP2 + sub*16 + 4*g] = z;
        }
      }
    }
    bf16x8 vf = *(const bf16x8*)&VT[l15*KPAD + cc*32 + 8*g];
    #pragma unroll
    for (int i = 0; i < 4; ++i) {
      int qt = p + 8*i;
      if (qt < 25) {
        bf16x8 pf = *(const bf16x8*)&P[w][i][l15*PP2 + 8*g];
        o[i] = __builtin_amdgcn_mfma_f32_16x16x32_bf16(vf, pf, o[i], 0, 0, 0);
      }
    }
  }

  #pragma unroll
  for (int i = 0; i < 4; ++i) {
    lsum[i] += __shfl_xor(lsum[i], 16, 64);
    lsum[i] += __shfl_xor(lsum[i], 32, 64);
  }

  __syncthreads();
  float* CB = (float*)&P[0][0][0];
  if (hh == 1) {
    #pragma unroll
    for (int i = 0; i < 4; ++i) {
      int qt = p + 8*i;
      if (qt < 25) {
        int base = (((p*4) + i)*64 + lane)*5;
        CB[base+0] = o[i][0]; CB[base+1] = o[i][1];
        CB[base+2] = o[i][2]; CB[base+3] = o[i][3];
        CB[base+4] = lsum[i];
      }
    }
  }
  __syncthreads();
  if (hh == 0) {
    const int b = bh >> 3, h = bh & 7;
    #pragma unroll
    for (int i = 0; i < 4; ++i) {
      int qt = p + 8*i;
      if (qt < 25) {
        int base = (((p*4) + i)*64 + lane)*5;
        float o0 = o[i][0] + CB[base+0];
        float o1 = o[i][1] + CB[base+1];
        float o2 = o[i][2] + CB[base+2];
        float o3 = o[i][3] + CB[base+3];
        float ls = lsum[i] + CB[base+4];
        float inv = 1.f / ls;
        uint2 pk;
        pk.x = pack2bf(o0*inv, o1*inv);
        pk.y = pack2bf(o2*inv, o3*inv);
        *(uint2*)&attn_b[((size_t)b*Nn + qt*16 + l15)*Dd + h*16 + 4*g] = pk;
      }
    }
  }
}

// ---------------- K3: output proj (MFMA) + residual + LN1 + gating, fused ----------------
// grid 200, block 256 (4 waves x 32 outdims; 64 tokens/block). Writes bf16 out1b only.
__global__ __launch_bounds__(256) void proj_ln1_gate_kernel(
    const float* __restrict__ x, const short* __restrict__ attn_b,
    const short* __restrict__ wo_t, const float* __restrict__ bo,
    const float* __restrict__ g1, const float* __restrict__ b1n,
    const float* __restrict__ w_gate,
    short* __restrict__ out1b,
    int* __restrict__ cnt, float* __restrict__ imp, float* __restrict__ loadv,
    int* __restrict__ etok, float* __restrict__ egate)
{
  __shared__ short as_[64][136];
  __shared__ float reds[4][64];
  __shared__ float reds2[4][64];
  __shared__ float mv[64][2];
  __shared__ float lgs[64*8];
  __shared__ float wgs[128*8];
  __shared__ float s_imp[8], s_load[8];
  __shared__ int s_cnt[8], s_base[8];

  const int tid = threadIdx.x;
  const int t0 = blockIdx.x * 64;

  #pragma unroll
  for (int it = 0; it < 8; ++it) {
    int lin = it * 256 + tid;
    int r = lin >> 5;
    int c4 = (lin & 31) << 2;
    *(uint2*)&as_[r][c4] = *(const uint2*)&attn_b[(size_t)(t0 + r) * Dd + c4];
  }
  #pragma unroll
  for (int it = 0; it < 4; ++it) wgs[it*256 + tid] = w_gate[it*256 + tid];
  lgs[tid] = 0.f; lgs[tid + 256] = 0.f;
  if (tid < 8) { s_imp[tid] = 0.f; s_load[tid] = 0.f; s_cnt[tid] = 0; }
  __syncthreads();

  const int lane = tid & 63, w = tid >> 6;
  const int l15 = lane & 15, l4 = lane >> 4;

  f32x4 zero4 = {0.f, 0.f, 0.f, 0.f};
  f32x4 y[2][4];
  #pragma unroll
  for (int dt = 0; dt < 2; ++dt)
    #pragma unroll
    for (int mt = 0; mt < 4; ++mt) y[dt][mt] = zero4;

  #pragma unroll
  for (int kt = 0; kt < 4; ++kt) {
    bf16x8 a0 = *(const bf16x8*)&wo_t[(size_t)(w*32 + l15) * Dd + kt*32 + l4*8];
    bf16x8 a1 = *(const bf16x8*)&wo_t[(size_t)(w*32 + 16 + l15) * Dd + kt*32 + l4*8];
    bf16x8 bm[4];
    #pragma unroll
    for (int mt = 0; mt < 4; ++mt)
      bm[mt] = *(const bf16x8*)&as_[mt*16 + l15][kt*32 + l4*8];
    #pragma unroll
    for (int mt = 0; mt < 4; ++mt) {
      y[0][mt] = __builtin_amdgcn_mfma_f32_16x16x32_bf16(a0, bm[mt], y[0][mt], 0, 0, 0);
      y[1][mt] = __builtin_amdgcn_mfma_f32_16x16x32_bf16(a1, bm[mt], y[1][mt], 0, 0, 0);
    }
  }

  float4 bov[2];
  bov[0] = *(const float4*)&bo[w*32 + 0*16 + l4*4];
  bov[1] = *(const float4*)&bo[w*32 + 1*16 + l4*4];
  float sP[4], s2P[4];
  #pragma unroll
  for (int mt = 0; mt < 4; ++mt) { sP[mt] = 0.f; s2P[mt] = 0.f; }
  #pragma unroll
  for (int mt = 0; mt < 4; ++mt) {
    int row = mt*16 + l15;
    #pragma unroll
    for (int dt = 0; dt < 2; ++dt) {
      int dim = w*32 + dt*16 + l4*4;
      float4 xv = *(const float4*)&x[(size_t)(t0 + row) * Dd + dim];
      float4 bv = bov[dt];
      f32x4 r = y[dt][mt];
      r[0] += bv.x + xv.x; r[1] += bv.y + xv.y;
      r[2] += bv.z + xv.z; r[3] += bv.w + xv.w;
      y[dt][mt] = r;
      sP[mt]  += (r[0] + r[1]) + (r[2] + r[3]);
      s2P[mt] += (r[0]*r[0] + r[1]*r[1]) + (r[2]*r[2] + r[3]*r[3]);
    }
  }
  #pragma unroll
  for (int mt = 0; mt < 4; ++mt) {
    sP[mt]  += __shfl_xor(sP[mt], 16, 64);  sP[mt]  += __shfl_xor(sP[mt], 32, 64);
    s2P[mt] += __shfl_xor(s2P[mt], 16, 64); s2P[mt] += __shfl_xor(s2P[mt], 32, 64);
  }
  if (l4 == 0) {
    #pragma unroll
    for (int mt = 0; mt < 4; ++mt) {
      reds[w][mt*16 + l15] = sP[mt];
      reds2[w][mt*16 + l15] = s2P[mt];
    }
  }
  __syncthreads();
  if (tid < 64) {
    float s = reds[0][tid] + reds[1][tid] + reds[2][tid] + reds[3][tid];
    float s2 = reds2[0][tid] + reds2[1][tid] + reds2[2][tid] + reds2[3][tid];
    float m = s * (1.f/128.f);
    float var = s2 * (1.f/128.f) - m*m;
    mv[tid][0] = m;
    mv[tid][1] = rsqrtf(var + 1e-5f);
  }
  __syncthreads();

  float4 gv[2], bv2[2];
  #pragma unroll
  for (int dt = 0; dt < 2; ++dt) {
    gv[dt]  = *(const float4*)&g1[w*32 + dt*16 + l4*4];
    bv2[dt] = *(const float4*)&b1n[w*32 + dt*16 + l4*4];
  }
  #pragma unroll
  for (int mt = 0; mt < 4; ++mt) {
    int row = mt*16 + l15;
    float m = mv[row][0], inv = mv[row][1];
    float lg[8];
    #pragma unroll
    for (int e = 0; e < 8; ++e) lg[e] = 0.f;
    #pragma unroll
    for (int dt = 0; dt < 2; ++dt) {
      int dim = w*32 + dt*16 + l4*4;
      f32x4 r = y[dt][mt];
      float o0 = (r[0]-m)*inv*((float*)&gv[dt])[0] + ((float*)&bv2[dt])[0];
      float o1 = (r[1]-m)*inv*((float*)&gv[dt])[1] + ((float*)&bv2[dt])[1];
      float o2 = (r[2]-m)*inv*((float*)&gv[dt])[2] + ((float*)&bv2[dt])[2];
      float o3 = (r[3]-m)*inv*((float*)&gv[dt])[3] + ((float*)&bv2[dt])[3];
      uint2 p; p.x = pack2bf(o0, o1); p.y = pack2bf(o2, o3);
      *(uint2*)&out1b[(size_t)(t0 + row) * Dd + dim] = p;
      #pragma unroll
      for (int e = 0; e < 8; ++e)
        lg[e] += o0*wgs[(dim+0)*8+e] + o1*wgs[(dim+1)*8+e]
               + o2*wgs[(dim+2)*8+e] + o3*wgs[(dim+3)*8+e];
    }
    #pragma unroll
    for (int e = 0; e < 8; ++e) {
      lg[e] += __shfl_xor(lg[e], 16, 64);
      lg[e] += __shfl_xor(lg[e], 32, 64);
    }
    if (l4 == 0) {
      #pragma unroll
      for (int e = 0; e < 8; ++e) atomicAdd(&lgs[row*8 + e], lg[e]);
    }
  }
  __syncthreads();

  int i0 = 0, i1 = -1, p0 = 0, p1 = 0;
  float g0 = 0.f, gg1 = 0.f;
  if (tid < 64) {
    float lgv[8];
    #pragma unroll
    for (int e = 0; e < 8; ++e) lgv[e] = lgs[tid*8 + e];
    float v0 = lgv[0];
    #pragma unroll
    for (int e = 1; e < 8; ++e) if (lgv[e] > v0) { v0 = lgv[e]; i0 = e; }
    float v1 = -INFINITY;
    #pragma unroll
    for (int e = 0; e < 8; ++e) if (e != i0 && lgv[e] > v1) { v1 = lgv[e]; i1 = e; }
    g0 = 1.f / (1.f + __expf(v1 - v0));
    gg1 = 1.f - g0;
    atomicAdd(&s_imp[i0], g0);  atomicAdd(&s_imp[i1], gg1);
    atomicAdd(&s_load[i0], 1.f); atomicAdd(&s_load[i1], 1.f);
    p0 = atomicAdd(&s_cnt[i0], 1);
    p1 = atomicAdd(&s_cnt[i1], 1);
  }
  __syncthreads();
  if (tid < 8) {
    s_base[tid] = atomicAdd(&cnt[tid], s_cnt[tid]);
    atomicAdd(&imp[tid], s_imp[tid]);
    atomicAdd(&loadv[tid], s_load[tid]);
  }
  __syncthreads();
  if (tid < 64) {
    int t = t0 + tid;
    int o0 = i0 * Tt + s_base[i0] + p0;
    etok[o0] = t;               egate[o0] = g0;
    int o1 = i1 * Tt + s_base[i1] + p1;
    etok[o1] = t | (1 << 30);   egate[o1] = gg1;
  }
}

// ---------------- K6: grouped sparse MoE FFN — chunk-split, 8 waves ----------------
// grid (200, 8), block 512. Wave-group grp = w>>2 handles FF-chunks {2grp, 2grp+1} with
// its own hs buffer; partial GEMM2 y summed via padded LDS (exact float add).
union MoeShared {
  struct { short xs[64][136]; short hs[2][64][136]; } s;   // 52224 B
  float comb[4][64][36];                                   // 36864 B (aligned: 36*4=144B row)
};

__global__ __launch_bounds__(512) void moe_kernel(const short* __restrict__ out1b,
    const short* __restrict__ W1t, const float* __restrict__ b1,
    const short* __restrict__ W2t, const float* __restrict__ b2,
    const int* __restrict__ cnt, const int* __restrict__ etok, const float* __restrict__ egate,
    short* __restrict__ moe0, short* __restrict__ moe1)
{
  __shared__ MoeShared su;
  __shared__ int els[64];
  __shared__ float gls[64];

  const int e = blockIdx.y;
  const int count = cnt[e];
  const int t0 = blockIdx.x * 64;
  if (t0 >= count) return;
  const int nt = min(64, count - t0);
  const int tid = threadIdx.x;

  if (tid < 64) {
    int idx = (tid < nt) ? tid : 0;
    els[tid] = etok[e * Tt + t0 + idx];
    gls[tid] = (tid < nt) ? egate[e * Tt + t0 + tid] : 0.f;
  }
  __syncthreads();

  #pragma unroll
  for (int it = 0; it < 4; ++it) {
    int lin = it * 512 + tid;
    int r = lin >> 5;
    int c4 = (lin & 31) << 2;
    int tok = els[r] & 0x3FFFFFFF;
    *(uint2*)&su.s.xs[r][c4] = *(const uint2*)&out1b[(size_t)tok * Dd + c4];
  }
  __syncthreads();

  const int lane = tid & 63;
  const int w = tid >> 6;
  const int grp = w >> 2;          // 0: chunks 0,1   1: chunks 2,3
  const int wp = w & 3;
  const int l15 = lane & 15;
  const int l4 = lane >> 4;

  f32x4 zero4 = {0.f, 0.f, 0.f, 0.f};
  f32x4 y[2][4];
  #pragma unroll
  for (int dt = 0; dt < 2; ++dt)
    #pragma unroll
    for (int mt = 0; mt < 4; ++mt) y[dt][mt] = zero4;

  const short* W1p = W1t + (size_t)e * FFd * Dd;
  const short* W2p = W2t + (size_t)e * Dd * FFd;
  short (*hsg)[136] = su.s.hs[grp];

  #pragma unroll
  for (int c = 0; c < 2; ++c) {
    const int ch = grp*2 + c;
    f32x4 h[2][4];
    #pragma unroll
    for (int ft = 0; ft < 2; ++ft)
      #pragma unroll
      for (int mt = 0; mt < 4; ++mt) h[ft][mt] = zero4;

    #pragma unroll
    for (int kt = 0; kt < 4; ++kt) {
      bf16x8 a0 = *(const bf16x8*)&W1p[(size_t)(ch*128 + wp*32 + 0*16 + l15) * Dd + kt*32 + l4*8];
      bf16x8 a1 = *(const bf16x8*)&W1p[(size_t)(ch*128 + wp*32 + 1*16 + l15) * Dd + kt*32 + l4*8];
      bf16x8 bm[4];
      #pragma unroll
      for (int mt = 0; mt < 4; ++mt)
        bm[mt] = *(const bf16x8*)&su.s.xs[mt*16 + l15][kt*32 + l4*8];
      #pragma unroll
      for (int mt = 0; mt < 4; ++mt) {
        h[0][mt] = __builtin_amdgcn_mfma_f32_16x16x32_bf16(a0, bm[mt], h[0][mt], 0, 0, 0);
        h[1][mt] = __builtin_amdgcn_mfma_f32_16x16x32_bf16(a1, bm[mt], h[1][mt], 0, 0, 0);
      }
    }

    float4 b1v0 = *(const float4*)&b1[e*FFd + ch*128 + wp*32 + 0*16 + l4*4];
    float4 b1v1 = *(const float4*)&b1[e*FFd + ch*128 + wp*32 + 1*16 + l4*4];
    __syncthreads();   // prior GEMM2 reads of this group's hs done (both groups aligned)
    #pragma unroll
    for (int mt = 0; mt < 4; ++mt) {
      uint2 p0, p1;
      p0.x = pack2bf(fmaxf(h[0][mt][0] + b1v0.x, 0.f), fmaxf(h[0][mt][1] + b1v0.y, 0.f));
      p0.y = pack2bf(fmaxf(h[0][mt][2] + b1v0.z, 0.f), fmaxf(h[0][mt][3] + b1v0.w, 0.f));
      *(uint2*)&hsg[mt*16 + l15][wp*32 + 0*16 + l4*4] = p0;
      p1.x = pack2bf(fmaxf(h[1][mt][0] + b1v1.x, 0.f), fmaxf(h[1][mt][1] + b1v1.y, 0.f));
      p1.y = pack2bf(fmaxf(h[1][mt][2] + b1v1.z, 0.f), fmaxf(h[1][mt][3] + b1v1.w, 0.f));
      *(uint2*)&hsg[mt*16 + l15][wp*32 + 1*16 + l4*4] = p1;
    }
    __syncthreads();

    #pragma unroll
    for (int kt = 0; kt < 4; ++kt) {
      bf16x8 a0 = *(const bf16x8*)&W2p[(size_t)(wp*32 + 0*16 + l15) * FFd + ch*128 + kt*32 + l4*8];
      bf16x8 a1 = *(const bf16x8*)&W2p[(size_t)(wp*32 + 1*16 + l15) * FFd + ch*128 + kt*32 + l4*8];
      bf16x8 bm[4];
      #pragma unroll
      for (int mt = 0; mt < 4; ++mt)
        bm[mt] = *(const bf16x8*)&hsg[mt*16 + l15][kt*32 + l4*8];
      #pragma unroll
      for (int mt = 0; mt < 4; ++mt) {
        y[0][mt] = __builtin_amdgcn_mfma_f32_16x16x32_bf16(a0, bm[mt], y[0][mt], 0, 0, 0);
        y[1][mt] = __builtin_amdgcn_mfma_f32_16x16x32_bf16(a1, bm[mt], y[1][mt], 0, 0, 0);
      }
    }
  }

  // combine partial y across the two wave-groups (exact float add)
  __syncthreads();   // all GEMM1/GEMM2 done; xs/hs free for reuse
  if (grp == 1) {
    float* cb = &su.comb[wp][lane][0];
    #pragma unroll
    for (int dt = 0; dt < 2; ++dt)
      #pragma unroll
      for (int mt = 0; mt < 4; ++mt) {
        float4 v4;
        v4.x = y[dt][mt][0]; v4.y = y[dt][mt][1];
        v4.z = y[dt][mt][2]; v4.w = y[dt][mt][3];
        *(float4*)&cb[(dt*4+mt)*4] = v4;
      }
  }
  __syncthreads();
  if (grp == 0) {
    const float* cb = &su.comb[wp][lane][0];
    float4 b2v[2];
    b2v[0] = *(const float4*)&b2[e*Dd + wp*32 + 0*16 + l4*4];
    b2v[1] = *(const float4*)&b2[e*Dd + wp*32 + 1*16 + l4*4];
    #pragma unroll
    for (int mt = 0; mt < 4; ++mt) {
      int m = mt*16 + l15;
      if (m < nt) {
        int raw = els[m];
        int t = raw & 0x3FFFFFFF;
        float g = gls[m];
        short* basep = (raw & (1 << 30)) ? moe1 : moe0;
        #pragma unroll
        for (int dt = 0; dt < 2; ++dt) {
          float4 yo = *(const float4*)&cb[(dt*4+mt)*4];
          float v0 = g * (y[dt][mt][0] + yo.x + ((dt == 0) ? b2v[0].x : b2v[1].x));
          float v1 = g * (y[dt][mt][1] + yo.y + ((dt == 0) ? b2v[0].y : b2v[1].y));
          float v2 = g * (y[dt][mt][2] + yo.z + ((dt == 0) ? b2v[0].z : b2v[1].z));
          float v3 = g * (y[dt][mt][3] + yo.w + ((dt == 0) ? b2v[0].w : b2v[1].w));
          uint2 p; p.x = pack2bf(v0, v1); p.y = pack2bf(v2, v3);
          *(uint2*)&basep[(size_t)t * Dd + wp*32 + dt*16 + l4*4] = p;
        }
      }
    }
  }
}

// ---------------- K7: residual (bf16) + LN2 -> d_out (+ loss in block 0) ----------------
// grid 3200, block 256 (one wave per token; no LDS).
__global__ __launch_bounds__(256) void ln2_kernel(const short* __restrict__ out1b,
    const short* __restrict__ moe0, const short* __restrict__ moe1,
    const float* __restrict__ g, const float* __restrict__ bb,
    const float* __restrict__ imp, const float* __restrict__ loadv,
    float* __restrict__ out, float* __restrict__ out_loss)
{
  const int tid = threadIdx.x;
  const int lane = tid & 63;
  const int t = blockIdx.x * 4 + (tid >> 6);
  const int j = lane * 2;

  unsigned xo = *(const unsigned*)&out1b[(size_t)t * Dd + j];
  unsigned m0 = *(const unsigned*)&moe0[(size_t)t * Dd + j];
  unsigned m1 = *(const unsigned*)&moe1[(size_t)t * Dd + j];
  union { unsigned u; float f; } xa, xb, a, b, c, d;
  xa.u = xo << 16; xb.u = xo & 0xFFFF0000u;
  a.u = m0 << 16; b.u = m0 & 0xFFFF0000u;
  c.u = m1 << 16; d.u = m1 & 0xFFFF0000u;
  float r0 = xa.f + a.f + c.f;
  float r1 = xb.f + b.f + d.f;

  float s = r0 + r1;
  float s2 = r0*r0 + r1*r1;
  #pragma unroll
  for (int off = 32; off > 0; off >>= 1) {
    s  += __shfl_xor(s, off, 64);
    s2 += __shfl_xor(s2, off, 64);
  }
  float mean = s * (1.f/128.f);
  float var = s2 * (1.f/128.f) - mean*mean;
  float inv = rsqrtf(var + 1e-5f);
  float2 ov;
  ov.x = (r0 - mean) * inv * g[j]   + bb[j];
  ov.y = (r1 - mean) * inv * g[j+1] + bb[j+1];
  *(float2*)&out[(size_t)t * Dd + j] = ov;

  if (blockIdx.x == 0 && tid == 0) {
    float m1s = 0.f;
    for (int e = 0; e < 8; ++e) m1s += imp[e];
    m1s *= 0.125f;
    float v1 = 0.f;
    for (int e = 0; e < 8; ++e) { float dd = imp[e] - m1s; v1 += dd * dd; }
    v1 *= 0.125f;
    float c1 = v1 / (m1s * m1s + 1e-10f);
    float m2 = 0.f;
    for (int e = 0; e < 8; ++e) m2 += loadv[e];
    m2 *= 0.125f;
    float v2 = 0.f;
    for (int e = 0; e < 8; ++e) { float dd = loadv[e] - m2; v2 += dd * dd; }
    v2 *= 0.125f;
    float c2 = v2 / (m2 * m2 + 1e-10f);
    out_loss[0] = (c1 + c2) * 0.01f;
  }
}

extern "C" void kernel_launch(void* const* d_in, const int* in_sizes, int n_in,
                              void* d_out, int out_size, void* d_ws, size_t ws_size,
                              hipStream_t stream)
{
  (void)in_sizes; (void)n_in; (void)out_size; (void)ws_size;
  const float* x      = (const float*)d_in[0];
  const float* Wq     = (const float*)d_in[1];
  const float* Wk     = (const float*)d_in[2];
  const float* Wv     = (const float*)d_in[3];
  const float* Wo     = (const float*)d_in[4];
  const float* bo     = (const float*)d_in[5];
  const float* ln1_g  = (const float*)d_in[6];
  const float* ln1_b  = (const float*)d_in[7];
  const float* w_gate = (const float*)d_in[8];
  const float* W1     = (const float*)d_in[9];
  const float* b1     = (const float*)d_in[10];
  const float* W2     = (const float*)d_in[11];
  const float* b2     = (const float*)d_in[12];
  const float* ln2_g  = (const float*)d_in[13];
  const float* ln2_b  = (const float*)d_in[14];

  char* wsb = (char*)d_ws;
  size_t off = 0;
  short* attn_b  = (short*)(wsb + off); off += (size_t)Tt*Dd*2;          //  3,276,800
  short* out1b   = (short*)(wsb + off); off += (size_t)Tt*Dd*2;          //  3,276,800
  short* moe0    = (short*)(wsb + off); off += (size_t)Tt*Dd*2;          //  3,276,800
  short* moe1    = (short*)(wsb + off); off += (size_t)Tt*Dd*2;          //  3,276,800
  short* q_bf    = (short*)(wsb + off); off += (size_t)256*400*16*2;     //  3,276,800
  short* k_bf    = (short*)(wsb + off); off += (size_t)256*400*16*2;     //  3,276,800
  short* v_bf    = (short*)(wsb + off); off += (size_t)256*400*16*2;     //  3,276,800
  short* W1t     = (short*)(wsb + off); off += (size_t)Ee*FFd*Dd*2;      //  1,048,576
  short* W2t     = (short*)(wsb + off); off += (size_t)Ee*FFd*Dd*2;      //  1,048,576
  short* wo_t    = (short*)(wsb + off); off += (size_t)Dd*Dd*2;          //     32,768
  short* qkvw    = (short*)(wsb + off); off += (size_t)384*Dd*2;         //     98,304
  int*   gmeta   = (int*)(wsb + off);   off += 256;
  int*   etok    = (int*)(wsb + off);   off += (size_t)Ee*Tt*4;          //    409,600
  float* egate   = (float*)(wsb + off); off += (size_t)Ee*Tt*4;          //    409,600

  int*   cnt   = gmeta;
  float* imp   = (float*)(gmeta + 8);
  float* loadv = (float*)(gmeta + 16);

  float* out3 = (float*)d_out;
  float* loss = out3 + Tt * Dd;

  prep_kernel<<<1088, 256, 0, stream>>>(W1, W2, Wo, Wq, Wk, Wv, W1t, W2t, wo_t, qkvw, gmeta);
  qkv_kernel<<<200, 512, 0, stream>>>(x, qkvw, q_bf, k_bf, v_bf);
  attn_kernel<<<256, 1024, 0, stream>>>(q_bf, k_bf, v_bf, attn_b);
  proj_ln1_gate_kernel<<<200, 256, 0, stream>>>(x, attn_b, wo_t, bo, ln1_g, ln1_b, w_gate,
                                                out1b, cnt, imp, loadv, etok, egate);
  moe_kernel<<<dim3(200, 8), 512, 0, stream>>>(out1b, W1t, b1, W2t, b2, cnt, etok, egate, moe0, moe1);
  ln2_kernel<<<3200, 256, 0, stream>>>(out1b, moe0, moe1, ln2_g, ln2_b, imp, loadv, out3, loss);
}